// Round 1
// baseline (1849.275 us; speedup 1.0000x reference)
//
#include <hip/hip_runtime.h>
#include <hip/hip_bf16.h>

// ---------------------------------------------------------------------------
// GAT 2-layer, N=16384 nodes (SEQ=1024 x BSZ=16), D=512, H=8, E=524288 edges
// Layer0: C=64 concat -> direct message aggregation of h0 = nodes@W0
// Layer1: C=512 mean  -> aggregate-then-GEMM (never materialize h1[N,4096])
// ---------------------------------------------------------------------------

#define NNODES 16384

__global__ void zero_k(int* p, int n) {
    int i = blockIdx.x * 256 + threadIdx.x;
    if (i < n) p[i] = 0;
}

__global__ void count_k(const int* __restrict__ dst, int E, int* __restrict__ deg) {
    int i = blockIdx.x * 256 + threadIdx.x;
    if (i < E) atomicAdd(&deg[dst[i]], 1);
}

// single-block exclusive scan over N=16384 (1024 threads x 16 each)
__global__ __launch_bounds__(1024) void scan_k(const int* __restrict__ deg,
                                               int* __restrict__ indptr,
                                               int* __restrict__ cursor, int n) {
    __shared__ int sums[1024];
    int t = threadIdx.x;
    int base = t * 16;
    int local[16];
    int s = 0;
    #pragma unroll
    for (int i = 0; i < 16; i++) { local[i] = s; s += deg[base + i]; }
    sums[t] = s;
    __syncthreads();
    for (int off = 1; off < 1024; off <<= 1) {
        int v = (t >= off) ? sums[t - off] : 0;
        __syncthreads();
        sums[t] += v;
        __syncthreads();
    }
    int base_sum = (t == 0) ? 0 : sums[t - 1];
    #pragma unroll
    for (int i = 0; i < 16; i++) {
        int v = base_sum + local[i];
        indptr[base + i] = v;
        cursor[base + i] = v;
    }
    if (t == 1023) indptr[n] = base_sum + s;
}

__global__ void scatter_k(const int* __restrict__ src, const int* __restrict__ dst,
                          int E, int* __restrict__ cursor, int* __restrict__ csr) {
    int i = blockIdx.x * 256 + threadIdx.x;
    if (i < E) {
        int pos = atomicAdd(&cursor[dst[i]], 1);
        csr[pos] = src[i];
    }
}

// ---------------------------------------------------------------------------
// f32 GEMM, 128x128 tile, BK=16, 256 threads, 8x8 per thread. Ncols fixed 512.
// MODE 0: A rows gathered from x with node permutation (n=g*1024+s -> x row s*16+g)
// MODE 1: A row-major stride K; epilogue +bias, ELU (layer-1 final output)
// ---------------------------------------------------------------------------
template <int MODE>
__global__ __launch_bounds__(256) void gemm_k(const float* __restrict__ A,
                                              const float* __restrict__ B,
                                              float* __restrict__ C, int M, int K,
                                              const float* __restrict__ bias) {
    __shared__ float As[16][132];
    __shared__ float Bs[16][132];
    int t = threadIdx.x;
    int tx = t & 15, ty = t >> 4;
    int row0 = blockIdx.y * 128, col0 = blockIdx.x * 128;
    float acc[8][8] = {};

    for (int k0 = 0; k0 < K; k0 += 16) {
        #pragma unroll
        for (int i = 0; i < 2; i++) {
            int flat = t * 8 + i * 4;  // 0..2047 over 128 rows x 16 k
            int r = flat >> 4;
            int kk = flat & 15;
            int gr = row0 + r;
            long off;
            if (MODE == 0) {
                int g = gr >> 10, sI = gr & 1023;
                off = (long)(sI * 16 + g) * 512 + k0 + kk;
            } else {
                off = (long)gr * K + k0 + kk;
            }
            float4 v = *(const float4*)(A + off);
            As[kk + 0][r] = v.x;
            As[kk + 1][r] = v.y;
            As[kk + 2][r] = v.z;
            As[kk + 3][r] = v.w;
        }
        #pragma unroll
        for (int i = 0; i < 2; i++) {
            int kk = t >> 4;
            int c = (tx << 3) + (i << 2);
            float4 v = *(const float4*)(B + (long)(k0 + kk) * 512 + col0 + c);
            *(float4*)&Bs[kk][c] = v;
        }
        __syncthreads();
        #pragma unroll
        for (int kk = 0; kk < 16; kk++) {
            float a[8], b[8];
            *(float4*)&a[0] = *(const float4*)&As[kk][ty * 8];
            *(float4*)&a[4] = *(const float4*)&As[kk][ty * 8 + 4];
            *(float4*)&b[0] = *(const float4*)&Bs[kk][tx * 8];
            *(float4*)&b[4] = *(const float4*)&Bs[kk][tx * 8 + 4];
            #pragma unroll
            for (int i = 0; i < 8; i++)
                #pragma unroll
                for (int j = 0; j < 8; j++) acc[i][j] = fmaf(a[i], b[j], acc[i][j]);
        }
        __syncthreads();
    }

    #pragma unroll
    for (int i = 0; i < 8; i++) {
        long grow = row0 + ty * 8 + i;
        #pragma unroll
        for (int j = 0; j < 8; j += 4) {
            int gcol = col0 + tx * 8 + j;
            float4 v = make_float4(acc[i][j], acc[i][j + 1], acc[i][j + 2], acc[i][j + 3]);
            if (MODE == 1) {
                v.x += bias[gcol];
                v.y += bias[gcol + 1];
                v.z += bias[gcol + 2];
                v.w += bias[gcol + 3];
                v.x = v.x > 0.f ? v.x : __expf(v.x) - 1.f;
                v.y = v.y > 0.f ? v.y : __expf(v.y) - 1.f;
                v.z = v.z > 0.f ? v.z : __expf(v.z) - 1.f;
                v.w = v.w > 0.f ? v.w : __expf(v.w) - 1.f;
            }
            *(float4*)(C + grow * 512 + gcol) = v;
        }
    }
}

// alpha0: asrc/adst [N,8] from h0 (per-head 64-len dots). 1 wave per node.
__global__ __launch_bounds__(64) void alpha0_k(const float* __restrict__ h0,
                                               const float* __restrict__ att_s,
                                               const float* __restrict__ att_d,
                                               float* __restrict__ as_,
                                               float* __restrict__ ad_) {
    int n = blockIdx.x;
    int l = threadIdx.x;
    int h = l >> 3, i = l & 7;
    float ps = 0.f, pd = 0.f;
    #pragma unroll
    for (int c = 0; c < 64; c += 8) {
        float v = h0[(long)n * 512 + h * 64 + c + i];
        ps += v * att_s[h * 64 + c + i];
        pd += v * att_d[h * 64 + c + i];
    }
    #pragma unroll
    for (int off = 1; off < 8; off <<= 1) {
        ps += __shfl_xor(ps, off);
        pd += __shfl_xor(pd, off);
    }
    if (i == 0) {
        as_[n * 8 + h] = ps;
        ad_[n * 8 + h] = pd;
    }
}

// folded attention weights for layer1: ws1[k,h] = sum_c W1[k, h*512+c]*att[h,c]
__global__ __launch_bounds__(256) void prep1_k(const float* __restrict__ W1,
                                               const float* __restrict__ as1,
                                               const float* __restrict__ ad1,
                                               float* __restrict__ ws1,
                                               float* __restrict__ wd1) {
    int k = blockIdx.x;
    int t = threadIdx.x;
    int h = t >> 5, lane = t & 31;
    float ps = 0.f, pd = 0.f;
    for (int c = lane; c < 512; c += 32) {
        float w = W1[(long)k * 4096 + h * 512 + c];
        ps += w * as1[h * 512 + c];
        pd += w * ad1[h * 512 + c];
    }
    #pragma unroll
    for (int off = 1; off < 32; off <<= 1) {
        ps += __shfl_xor(ps, off);
        pd += __shfl_xor(pd, off);
    }
    if (lane == 0) {
        ws1[k * 8 + h] = ps;
        wd1[k * 8 + h] = pd;
    }
}

// alpha1: [N,8] = hl0 @ ws1/wd1
__global__ __launch_bounds__(256) void alpha1_k(const float* __restrict__ hl0,
                                                const float* __restrict__ ws1,
                                                const float* __restrict__ wd1,
                                                float* __restrict__ as_,
                                                float* __restrict__ ad_) {
    int n = blockIdx.x;
    int t = threadIdx.x;
    __shared__ float row[512];
    row[t] = hl0[(long)n * 512 + t];
    row[t + 256] = hl0[(long)n * 512 + t + 256];
    __syncthreads();
    int h = t >> 5, lane = t & 31;
    float ps = 0.f, pd = 0.f;
    for (int k = lane; k < 512; k += 32) {
        float v = row[k];
        ps += v * ws1[k * 8 + h];
        pd += v * wd1[k * 8 + h];
    }
    #pragma unroll
    for (int off = 1; off < 32; off <<= 1) {
        ps += __shfl_xor(ps, off);
        pd += __shfl_xor(pd, off);
    }
    if (lane == 0) {
        as_[n * 8 + h] = ps;
        ad_[n * 8 + h] = pd;
    }
}

// permuted + 1/8-scaled W1 for the layer-1 GEMM: B1p[h*512+k][c] = W1[k][h*512+c]/8
__global__ void permB1_k(const float* __restrict__ W1, float* __restrict__ B1p) {
    for (int idx = blockIdx.x * 256 + threadIdx.x; idx < 4096 * 512;
         idx += gridDim.x * 256) {
        int j = idx >> 9, c = idx & 511;
        int h = j >> 9, k = j & 511;
        B1p[idx] = W1[(long)k * 4096 + h * 512 + c] * 0.125f;
    }
}

// Layer-0 per-dst-node softmax + message aggregation (self-loop implicit).
// Output hl0 = elu(agg + b0).
__global__ __launch_bounds__(256) void node0_k(const float* __restrict__ h0,
                                               const float* __restrict__ asrc,
                                               const float* __restrict__ adst,
                                               const int* __restrict__ indptr,
                                               const int* __restrict__ csr,
                                               const float* __restrict__ b0,
                                               float* __restrict__ hl0) {
    int d = blockIdx.x;
    int t = threadIdx.x;
    __shared__ float red[256];
    __shared__ float m_s[8], rz_s[8];
    int e0 = indptr[d], ne = indptr[d + 1] - e0;
    int h = t & 7, slice = t >> 3;
    float adh = adst[d * 8 + h];

    // per-head max
    float mx = -3.0e38f;
    for (int e = slice; e < ne + 1; e += 32) {
        int s = (e < ne) ? csr[e0 + e] : d;
        float v = asrc[s * 8 + h] + adh;
        v = v > 0.f ? v : 0.2f * v;
        mx = fmaxf(mx, v);
    }
    red[t] = mx;
    __syncthreads();
    #pragma unroll
    for (int off = 128; off >= 8; off >>= 1) {
        if (t < off) red[t] = fmaxf(red[t], red[t + off]);
        __syncthreads();
    }
    if (t < 8) m_s[t] = red[t];
    __syncthreads();

    // per-head sum of exp
    float mh = m_s[h];
    float zs = 0.f;
    for (int e = slice; e < ne + 1; e += 32) {
        int s = (e < ne) ? csr[e0 + e] : d;
        float v = asrc[s * 8 + h] + adh;
        v = v > 0.f ? v : 0.2f * v;
        zs += __expf(v - mh);
    }
    red[t] = zs;
    __syncthreads();
    #pragma unroll
    for (int off = 128; off >= 8; off >>= 1) {
        if (t < off) red[t] += red[t + off];
        __syncthreads();
    }
    if (t < 8) rz_s[t] = 1.0f / (red[t] + 1e-16f);
    __syncthreads();

    // aggregate: thread owns channels t and t+256 (heads ha, ha+4)
    int ha = t >> 6, hb = ha + 4;
    float ma = m_s[ha], mb = m_s[hb];
    float ra = rz_s[ha], rb = rz_s[hb];
    float ada = adst[d * 8 + ha], adb = adst[d * 8 + hb];
    float acc0 = 0.f, acc1 = 0.f;
    for (int e = 0; e < ne + 1; e++) {
        int s = (e < ne) ? csr[e0 + e] : d;
        float ea = asrc[s * 8 + ha] + ada;
        ea = ea > 0.f ? ea : 0.2f * ea;
        float eb = asrc[s * 8 + hb] + adb;
        eb = eb > 0.f ? eb : 0.2f * eb;
        float pa = __expf(ea - ma) * ra;
        float pb = __expf(eb - mb) * rb;
        acc0 = fmaf(pa, h0[(long)s * 512 + t], acc0);
        acc1 = fmaf(pb, h0[(long)s * 512 + t + 256], acc1);
    }
    float o0 = acc0 + b0[t];
    float o1 = acc1 + b0[t + 256];
    o0 = o0 > 0.f ? o0 : __expf(o0) - 1.f;
    o1 = o1 > 0.f ? o1 : __expf(o1) - 1.f;
    hl0[(long)d * 512 + t] = o0;
    hl0[(long)d * 512 + t + 256] = o1;
}

// Layer-1 per-dst-node softmax + per-head raw-feature aggregation:
// agg[dloc, h*512+k] = sum_e alpha[e,h] * hl0[src_e, k]
__global__ __launch_bounds__(256) void node1_k(const float* __restrict__ hl0,
                                               const float* __restrict__ asrc,
                                               const float* __restrict__ adst,
                                               const int* __restrict__ indptr,
                                               const int* __restrict__ csr,
                                               float* __restrict__ agg, int base) {
    int d = base + blockIdx.x;
    int t = threadIdx.x;
    __shared__ float red[256];
    __shared__ float m_s[8], rz_s[8];
    __shared__ float al[32 * 8];
    __shared__ int sl[32];
    int e0 = indptr[d], ne = indptr[d + 1] - e0;
    int h = t & 7, slice = t >> 3;
    float adh = adst[d * 8 + h];

    float mx = -3.0e38f;
    for (int e = slice; e < ne + 1; e += 32) {
        int s = (e < ne) ? csr[e0 + e] : d;
        float v = asrc[s * 8 + h] + adh;
        v = v > 0.f ? v : 0.2f * v;
        mx = fmaxf(mx, v);
    }
    red[t] = mx;
    __syncthreads();
    #pragma unroll
    for (int off = 128; off >= 8; off >>= 1) {
        if (t < off) red[t] = fmaxf(red[t], red[t + off]);
        __syncthreads();
    }
    if (t < 8) m_s[t] = red[t];
    __syncthreads();

    float mh = m_s[h];
    float zs = 0.f;
    for (int e = slice; e < ne + 1; e += 32) {
        int s = (e < ne) ? csr[e0 + e] : d;
        float v = asrc[s * 8 + h] + adh;
        v = v > 0.f ? v : 0.2f * v;
        zs += __expf(v - mh);
    }
    red[t] = zs;
    __syncthreads();
    #pragma unroll
    for (int off = 128; off >= 8; off >>= 1) {
        if (t < off) red[t] += red[t + off];
        __syncthreads();
    }
    if (t < 8) rz_s[t] = 1.0f / (red[t] + 1e-16f);
    __syncthreads();

    float acc[8][2] = {};
    for (int eb = 0; eb < ne + 1; eb += 32) {
        int nn = min(32, ne + 1 - eb);
        __syncthreads();
        if (t < nn * 8) {  // t = el*8 + hh
            int el = t >> 3, hh = t & 7;
            int s = (eb + el < ne) ? csr[e0 + eb + el] : d;
            if (hh == 0) sl[el] = s;
            float v = asrc[s * 8 + hh] + adst[d * 8 + hh];
            v = v > 0.f ? v : 0.2f * v;
            al[t] = __expf(v - m_s[hh]) * rz_s[hh];
        }
        __syncthreads();
        for (int el = 0; el < nn; el++) {
            int s = sl[el];
            float v0 = hl0[(long)s * 512 + t];
            float v1 = hl0[(long)s * 512 + t + 256];
            #pragma unroll
            for (int hh = 0; hh < 8; hh++) {
                float a = al[el * 8 + hh];
                acc[hh][0] = fmaf(a, v0, acc[hh][0]);
                acc[hh][1] = fmaf(a, v1, acc[hh][1]);
            }
        }
    }
    long dl = blockIdx.x;
    #pragma unroll
    for (int hh = 0; hh < 8; hh++) {
        agg[dl * 4096 + hh * 512 + t] = acc[hh][0];
        agg[dl * 4096 + hh * 512 + t + 256] = acc[hh][1];
    }
}

extern "C" void kernel_launch(void* const* d_in, const int* in_sizes, int n_in,
                              void* d_out, int out_size, void* d_ws, size_t ws_size,
                              hipStream_t stream) {
    const float* x = (const float*)d_in[0];
    const int* ei = (const int*)d_in[1];
    const float* W0 = (const float*)d_in[2];
    const float* at_s0 = (const float*)d_in[3];
    const float* at_d0 = (const float*)d_in[4];
    const float* b0 = (const float*)d_in[5];
    const float* W1 = (const float*)d_in[6];
    const float* at_s1 = (const float*)d_in[7];
    const float* at_d1 = (const float*)d_in[8];
    const float* b1 = (const float*)d_in[9];
    float* out = (float*)d_out;

    const int N = NNODES;
    const int E = in_sizes[1] / 2;
    const int* esrc = ei;
    const int* edst = ei + E;

    char* p = (char*)d_ws;
    auto carve = [&](size_t bytes) -> void* {
        void* r = (void*)p;
        p += ((bytes + 255) & ~(size_t)255);
        return r;
    };
    float* h0 = (float*)carve((size_t)N * 512 * 4);
    float* hl0 = (float*)carve((size_t)N * 512 * 4);
    float* as0 = (float*)carve((size_t)N * 8 * 4);
    float* ad0 = (float*)carve((size_t)N * 8 * 4);
    float* as1 = (float*)carve((size_t)N * 8 * 4);
    float* ad1 = (float*)carve((size_t)N * 8 * 4);
    int* deg = (int*)carve((size_t)N * 4);
    int* indptr = (int*)carve((size_t)(N + 1) * 4);
    int* cursor = (int*)carve((size_t)N * 4);
    int* csr = (int*)carve((size_t)E * 4);
    float* ws1 = (float*)carve(512 * 8 * 4);
    float* wd1 = (float*)carve(512 * 8 * 4);
    float* B1p = (float*)carve((size_t)4096 * 512 * 4);
    size_t used = (size_t)(p - (char*)d_ws);

    int CH = 512;
    const int cands[5] = {16384, 8192, 4096, 2048, 1024};
    for (int ci = 0; ci < 5; ci++) {
        if (ws_size >= used + (size_t)cands[ci] * 4096 * 4 + 256) {
            CH = cands[ci];
            break;
        }
    }
    float* agg = (float*)carve((size_t)CH * 4096 * 4);

    // CSR build (by dst; self-loops handled implicitly in node kernels)
    zero_k<<<(N + 255) / 256, 256, 0, stream>>>(deg, N);
    count_k<<<(E + 255) / 256, 256, 0, stream>>>(edst, E, deg);
    scan_k<<<1, 1024, 0, stream>>>(deg, indptr, cursor, N);
    scatter_k<<<(E + 255) / 256, 256, 0, stream>>>(esrc, edst, E, cursor, csr);

    // Layer 0
    gemm_k<0><<<dim3(4, N / 128), 256, 0, stream>>>(x, W0, h0, N, 512, nullptr);
    alpha0_k<<<N, 64, 0, stream>>>(h0, at_s0, at_d0, as0, ad0);
    node0_k<<<N, 256, 0, stream>>>(h0, as0, ad0, indptr, csr, b0, hl0);

    // Layer 1 prep
    prep1_k<<<512, 256, 0, stream>>>(W1, at_s1, at_d1, ws1, wd1);
    alpha1_k<<<N, 256, 0, stream>>>(hl0, ws1, wd1, as1, ad1);
    permB1_k<<<2048, 256, 0, stream>>>(W1, B1p);

    // Layer 1: aggregate per chunk, then fused GEMM (+b1, ELU) into d_out
    for (int base = 0; base < N; base += CH) {
        node1_k<<<CH, 256, 0, stream>>>(hl0, as1, ad1, indptr, csr, agg, base);
        gemm_k<1><<<dim3(4, CH / 128), 256, 0, stream>>>(
            agg, B1p, out + (size_t)base * 512, CH, 4096, b1);
    }
}

// Round 2
// 980.056 us; speedup vs baseline: 1.8869x; 1.8869x over previous
//
#include <hip/hip_runtime.h>
#include <hip/hip_bf16.h>

// ---------------------------------------------------------------------------
// GAT 2-layer, N=16384 nodes, D=512, H=8, E=524288 edges (+self loops)
// GEMMs run as split-bf16 3-term MFMA (f32-accurate), node kernels do the
// CSR-grouped softmax + gather-aggregate.
// ---------------------------------------------------------------------------

#define NNODES 16384

typedef unsigned short u16;
typedef unsigned int u32;
typedef __attribute__((ext_vector_type(8))) __bf16 bf16x8;
typedef __attribute__((ext_vector_type(4))) float f32x4;

__device__ __forceinline__ u16 f2bf(float v) {
    u32 u = __builtin_bit_cast(u32, v);
    u32 r = (u + 0x7fffu + ((u >> 16) & 1u)) >> 16;
    return (u16)r;
}
__device__ __forceinline__ float bf2f(u16 s) {
    u32 u = ((u32)s) << 16;
    return __builtin_bit_cast(float, u);
}
__device__ __forceinline__ void split2(float v, u16& h, u16& l) {
    h = f2bf(v);
    l = f2bf(v - bf2f(h));
}

// ------------------------------ CSR build ---------------------------------
__global__ void zero_k(int* p, int n) {
    int i = blockIdx.x * 256 + threadIdx.x;
    if (i < n) p[i] = 0;
}

__global__ void count_k(const int* __restrict__ dst, int E, int* __restrict__ deg) {
    int i = blockIdx.x * 256 + threadIdx.x;
    if (i < E) atomicAdd(&deg[dst[i]], 1);
}

__global__ __launch_bounds__(1024) void scan_k(const int* __restrict__ deg,
                                               int* __restrict__ indptr,
                                               int* __restrict__ cursor, int n) {
    __shared__ int sums[1024];
    int t = threadIdx.x;
    int base = t * 16;
    int local[16];
    int s = 0;
    #pragma unroll
    for (int i = 0; i < 16; i++) { local[i] = s; s += deg[base + i]; }
    sums[t] = s;
    __syncthreads();
    for (int off = 1; off < 1024; off <<= 1) {
        int v = (t >= off) ? sums[t - off] : 0;
        __syncthreads();
        sums[t] += v;
        __syncthreads();
    }
    int base_sum = (t == 0) ? 0 : sums[t - 1];
    #pragma unroll
    for (int i = 0; i < 16; i++) {
        int v = base_sum + local[i];
        indptr[base + i] = v;
        cursor[base + i] = v;
    }
    if (t == 1023) indptr[n] = base_sum + s;
}

__global__ void scatter_k(const int* __restrict__ src, const int* __restrict__ dst,
                          int E, int* __restrict__ cursor, int* __restrict__ csr) {
    int i = blockIdx.x * 256 + threadIdx.x;
    if (i < E) {
        int pos = atomicAdd(&cursor[dst[i]], 1);
        csr[pos] = src[i];
    }
}

// ------------------------- split-bf16 prep kernels -------------------------
// xp[n][k] = x[(s*16+g)*512+k], n = g*1024+s  (node permutation applied)
__global__ void prepx_k(const float* __restrict__ x, u16* __restrict__ xh,
                        u16* __restrict__ xl) {
    int idx = blockIdx.x * 256 + threadIdx.x;  // one per 4 elements
    int e = idx << 2;
    int n = e >> 9, k = e & 511;
    int g = n >> 10, s = n & 1023;
    float4 v = *(const float4*)(x + ((size_t)(s * 16 + g) << 9) + k);
    u16 h[4], l[4];
    split2(v.x, h[0], l[0]);
    split2(v.y, h[1], l[1]);
    split2(v.z, h[2], l[2]);
    split2(v.w, h[3], l[3]);
    size_t o = ((size_t)n << 9) + k;
    *(ushort4*)(xh + o) = make_ushort4(h[0], h[1], h[2], h[3]);
    *(ushort4*)(xl + o) = make_ushort4(l[0], l[1], l[2], l[3]);
}

// W0t[n][k] = W0[k][n]
__global__ __launch_bounds__(256) void prepW0_k(const float* __restrict__ W0,
                                                u16* __restrict__ Wh,
                                                u16* __restrict__ Wl) {
    int n = blockIdx.x;
    for (int k = threadIdx.x; k < 512; k += 256) {
        float v = W0[(size_t)k * 512 + n];
        u16 h, l;
        split2(v, h, l);
        Wh[(size_t)n * 512 + k] = h;
        Wl[(size_t)n * 512 + k] = l;
    }
}

// B1t[c][h*512+k] = W1[k][h*512+c] / 8
__global__ __launch_bounds__(256) void prepW1_k(const float* __restrict__ W1,
                                                u16* __restrict__ Bh,
                                                u16* __restrict__ Bl) {
    int c = blockIdx.x;
    for (int j = threadIdx.x; j < 4096; j += 256) {
        int hh = j >> 9, k = j & 511;
        float v = W1[(size_t)k * 4096 + hh * 512 + c] * 0.125f;
        u16 h, l;
        split2(v, h, l);
        Bh[(size_t)c * 4096 + j] = h;
        Bl[(size_t)c * 4096 + j] = l;
    }
}

// ---------------------------------------------------------------------------
// Split-bf16 MFMA GEMM: C[M,512] = A[M,K] @ Bt[512,K]^T  (3 MFMA per frag pair)
// 128x128 tile, BK=32, 4 waves, 16x16x32 bf16 MFMA, LDS rows padded to 40 u16.
// MODE 0: plain f32 store. MODE 1: +bias, ELU.
// ---------------------------------------------------------------------------
template <int MODE>
__global__ __launch_bounds__(256) void mgemm_k(
    const u16* __restrict__ Ah, const u16* __restrict__ Al,
    const u16* __restrict__ Bh, const u16* __restrict__ Bl,
    float* __restrict__ C, int K, const float* __restrict__ bias) {
    __shared__ u16 sAh[128 * 40], sAl[128 * 40], sBh[128 * 40], sBl[128 * 40];
    int t = threadIdx.x;
    int lane = t & 63, w = t >> 6;
    int wr = w >> 1, wc = w & 1;
    int row0 = blockIdx.y * 128, col0 = blockIdx.x * 128;

    f32x4 acc[4][4];
    #pragma unroll
    for (int i = 0; i < 4; i++)
        #pragma unroll
        for (int j = 0; j < 4; j++) acc[i][j] = (f32x4){0.f, 0.f, 0.f, 0.f};

    int srow = t >> 2;   // 0..63: staging row within half-tile
    int sslot = t & 3;   // 16B slot within 64B row

    for (int k0 = 0; k0 < K; k0 += 32) {
        // stage 4 planes: 128 rows x 32 bf16 each
        #pragma unroll
        for (int hf = 0; hf < 2; hf++) {
            int r = srow + hf * 64;
            size_t ga = (size_t)(row0 + r) * K + k0 + sslot * 8;
            size_t gb = (size_t)(col0 + r) * K + k0 + sslot * 8;
            int lo = r * 40 + sslot * 8;
            int4 vah = *(const int4*)(Ah + ga);
            int4 val = *(const int4*)(Al + ga);
            int4 vbh = *(const int4*)(Bh + gb);
            int4 vbl = *(const int4*)(Bl + gb);
            *(int4*)(sAh + lo) = vah;
            *(int4*)(sAl + lo) = val;
            *(int4*)(sBh + lo) = vbh;
            *(int4*)(sBl + lo) = vbl;
        }
        __syncthreads();

        bf16x8 afh[4], afl[4], bfh[4], bfl[4];
        int arow = wr * 64 + (lane & 15);
        int brow = wc * 64 + (lane & 15);
        int kb = lane >> 4;
        #pragma unroll
        for (int f = 0; f < 4; f++) {
            int ra = (arow + f * 16) * 40 + kb * 8;
            int rb = (brow + f * 16) * 40 + kb * 8;
            afh[f] = *(const bf16x8*)(sAh + ra);
            afl[f] = *(const bf16x8*)(sAl + ra);
            bfh[f] = *(const bf16x8*)(sBh + rb);
            bfl[f] = *(const bf16x8*)(sBl + rb);
        }
        #pragma unroll
        for (int i = 0; i < 4; i++)
            #pragma unroll
            for (int j = 0; j < 4; j++) {
                acc[i][j] = __builtin_amdgcn_mfma_f32_16x16x32_bf16(afl[i], bfh[j], acc[i][j], 0, 0, 0);
                acc[i][j] = __builtin_amdgcn_mfma_f32_16x16x32_bf16(afh[i], bfl[j], acc[i][j], 0, 0, 0);
                acc[i][j] = __builtin_amdgcn_mfma_f32_16x16x32_bf16(afh[i], bfh[j], acc[i][j], 0, 0, 0);
            }
        __syncthreads();
    }

    int cr = (lane >> 4) * 4;
    int cc = lane & 15;
    #pragma unroll
    for (int i = 0; i < 4; i++) {
        #pragma unroll
        for (int j = 0; j < 4; j++) {
            int col = col0 + wc * 64 + j * 16 + cc;
            float bv = (MODE == 1) ? bias[col] : 0.f;
            f32x4 v = acc[i][j];
            #pragma unroll
            for (int q = 0; q < 4; q++) {
                float o = v[q] + bv;
                if (MODE == 1) o = o > 0.f ? o : __expf(o) - 1.f;
                size_t grow = (size_t)(row0 + wr * 64 + i * 16 + cr + q);
                C[grow * 512 + col] = o;
            }
        }
    }
}

// ------------------------------ attention ---------------------------------
// alpha0: per-node per-head dots over C=64 channels of h0
__global__ __launch_bounds__(64) void alpha0_k(const float* __restrict__ h0,
                                               const float* __restrict__ att_s,
                                               const float* __restrict__ att_d,
                                               float* __restrict__ as_,
                                               float* __restrict__ ad_) {
    int n = blockIdx.x;
    int l = threadIdx.x;
    int h = l >> 3, i = l & 7;
    float ps = 0.f, pd = 0.f;
    #pragma unroll
    for (int c = 0; c < 64; c += 8) {
        float v = h0[(size_t)n * 512 + h * 64 + c + i];
        ps += v * att_s[h * 64 + c + i];
        pd += v * att_d[h * 64 + c + i];
    }
    #pragma unroll
    for (int off = 1; off < 8; off <<= 1) {
        ps += __shfl_xor(ps, off);
        pd += __shfl_xor(pd, off);
    }
    if (i == 0) {
        as_[n * 8 + h] = ps;
        ad_[n * 8 + h] = pd;
    }
}

// folded attention weights: ws1[k,h] = sum_c W1[k, h*512+c]*att[h,c]
__global__ __launch_bounds__(256) void prep1_k(const float* __restrict__ W1,
                                               const float* __restrict__ as1,
                                               const float* __restrict__ ad1,
                                               float* __restrict__ ws1,
                                               float* __restrict__ wd1) {
    int k = blockIdx.x;
    int t = threadIdx.x;
    int h = t >> 5, lane = t & 31;
    float ps = 0.f, pd = 0.f;
    for (int c = lane; c < 512; c += 32) {
        float w = W1[(size_t)k * 4096 + h * 512 + c];
        ps += w * as1[h * 512 + c];
        pd += w * ad1[h * 512 + c];
    }
    #pragma unroll
    for (int off = 1; off < 32; off <<= 1) {
        ps += __shfl_xor(ps, off);
        pd += __shfl_xor(pd, off);
    }
    if (lane == 0) {
        ws1[k * 8 + h] = ps;
        wd1[k * 8 + h] = pd;
    }
}

__global__ __launch_bounds__(256) void alpha1_k(const float* __restrict__ hl0,
                                                const float* __restrict__ ws1,
                                                const float* __restrict__ wd1,
                                                float* __restrict__ as_,
                                                float* __restrict__ ad_) {
    int n = blockIdx.x;
    int t = threadIdx.x;
    __shared__ float row[512];
    row[t] = hl0[(size_t)n * 512 + t];
    row[t + 256] = hl0[(size_t)n * 512 + t + 256];
    __syncthreads();
    int h = t >> 5, lane = t & 31;
    float ps = 0.f, pd = 0.f;
    for (int k = lane; k < 512; k += 32) {
        float v = row[k];
        ps += v * ws1[k * 8 + h];
        pd += v * wd1[k * 8 + h];
    }
    #pragma unroll
    for (int off = 1; off < 32; off <<= 1) {
        ps += __shfl_xor(ps, off);
        pd += __shfl_xor(pd, off);
    }
    if (lane == 0) {
        as_[n * 8 + h] = ps;
        ad_[n * 8 + h] = pd;
    }
}

// -------- layer-0 node kernel: softmax + aggregate h0, ELU(+b0) -> hl0 -----
__global__ __launch_bounds__(256) void node0_k(const float* __restrict__ h0,
                                               const float* __restrict__ asrc,
                                               const float* __restrict__ adst,
                                               const int* __restrict__ indptr,
                                               const int* __restrict__ csr,
                                               const float* __restrict__ b0,
                                               float* __restrict__ hl0) {
    int d = blockIdx.x;
    int t = threadIdx.x;
    __shared__ float red[256];
    __shared__ float m_s[8], rz_s[8];
    __shared__ float al[32 * 8];
    __shared__ int sl[32];
    int e0 = indptr[d], ne = indptr[d + 1] - e0;
    int h = t & 7, slice = t >> 3;
    float adh = adst[d * 8 + h];

    float mx = -3.0e38f;
    for (int e = slice; e < ne + 1; e += 32) {
        int s = (e < ne) ? csr[e0 + e] : d;
        float v = asrc[s * 8 + h] + adh;
        v = v > 0.f ? v : 0.2f * v;
        mx = fmaxf(mx, v);
    }
    red[t] = mx;
    __syncthreads();
    #pragma unroll
    for (int off = 128; off >= 8; off >>= 1) {
        if (t < off) red[t] = fmaxf(red[t], red[t + off]);
        __syncthreads();
    }
    if (t < 8) m_s[t] = red[t];
    __syncthreads();

    float mh = m_s[h];
    float zs = 0.f;
    for (int e = slice; e < ne + 1; e += 32) {
        int s = (e < ne) ? csr[e0 + e] : d;
        float v = asrc[s * 8 + h] + adh;
        v = v > 0.f ? v : 0.2f * v;
        zs += __expf(v - mh);
    }
    red[t] = zs;
    __syncthreads();
    #pragma unroll
    for (int off = 128; off >= 8; off >>= 1) {
        if (t < off) red[t] += red[t + off];
        __syncthreads();
    }
    if (t < 8) rz_s[t] = 1.0f / (red[t] + 1e-16f);
    __syncthreads();

    // aggregate: thread owns channels t (head t>>6) and t+256 (head 4+(t>>6))
    int ha = t >> 6, hb = ha + 4;
    float acc0 = 0.f, acc1 = 0.f;
    for (int eb = 0; eb < ne + 1; eb += 32) {
        int nn = min(32, ne + 1 - eb);
        __syncthreads();
        if (t < nn * 8) {  // t = el*8 + hh
            int el = t >> 3, hh = t & 7;
            int s = (eb + el < ne) ? csr[e0 + eb + el] : d;
            if (hh == 0) sl[el] = s;
            float v = asrc[s * 8 + hh] + adst[d * 8 + hh];
            v = v > 0.f ? v : 0.2f * v;
            al[t] = __expf(v - m_s[hh]) * rz_s[hh];
        }
        __syncthreads();
        for (int el = 0; el < nn; el++) {
            int s = sl[el];
            acc0 = fmaf(al[el * 8 + ha], h0[(size_t)s * 512 + t], acc0);
            acc1 = fmaf(al[el * 8 + hb], h0[(size_t)s * 512 + t + 256], acc1);
        }
    }
    float o0 = acc0 + b0[t];
    float o1 = acc1 + b0[t + 256];
    o0 = o0 > 0.f ? o0 : __expf(o0) - 1.f;
    o1 = o1 > 0.f ? o1 : __expf(o1) - 1.f;
    hl0[(size_t)d * 512 + t] = o0;
    hl0[(size_t)d * 512 + t + 256] = o1;
}

// -------- layer-1 node kernel: softmax + per-head aggregate -> split bf16 ---
__global__ __launch_bounds__(256) void node1_k(const float* __restrict__ hl0,
                                               const float* __restrict__ asrc,
                                               const float* __restrict__ adst,
                                               const int* __restrict__ indptr,
                                               const int* __restrict__ csr,
                                               u16* __restrict__ aggh,
                                               u16* __restrict__ aggl, int base) {
    int d = base + blockIdx.x;
    int t = threadIdx.x;
    __shared__ float red[256];
    __shared__ float m_s[8], rz_s[8];
    __shared__ float al[32 * 8];
    __shared__ int sl[32];
    int e0 = indptr[d], ne = indptr[d + 1] - e0;
    int h = t & 7, slice = t >> 3;
    float adh = adst[d * 8 + h];

    float mx = -3.0e38f;
    for (int e = slice; e < ne + 1; e += 32) {
        int s = (e < ne) ? csr[e0 + e] : d;
        float v = asrc[s * 8 + h] + adh;
        v = v > 0.f ? v : 0.2f * v;
        mx = fmaxf(mx, v);
    }
    red[t] = mx;
    __syncthreads();
    #pragma unroll
    for (int off = 128; off >= 8; off >>= 1) {
        if (t < off) red[t] = fmaxf(red[t], red[t + off]);
        __syncthreads();
    }
    if (t < 8) m_s[t] = red[t];
    __syncthreads();

    float mh = m_s[h];
    float zs = 0.f;
    for (int e = slice; e < ne + 1; e += 32) {
        int s = (e < ne) ? csr[e0 + e] : d;
        float v = asrc[s * 8 + h] + adh;
        v = v > 0.f ? v : 0.2f * v;
        zs += __expf(v - mh);
    }
    red[t] = zs;
    __syncthreads();
    #pragma unroll
    for (int off = 128; off >= 8; off >>= 1) {
        if (t < off) red[t] += red[t + off];
        __syncthreads();
    }
    if (t < 8) rz_s[t] = 1.0f / (red[t] + 1e-16f);
    __syncthreads();

    float acc[8][2] = {};
    for (int eb = 0; eb < ne + 1; eb += 32) {
        int nn = min(32, ne + 1 - eb);
        __syncthreads();
        if (t < nn * 8) {
            int el = t >> 3, hh = t & 7;
            int s = (eb + el < ne) ? csr[e0 + eb + el] : d;
            if (hh == 0) sl[el] = s;
            float v = asrc[s * 8 + hh] + adst[d * 8 + hh];
            v = v > 0.f ? v : 0.2f * v;
            al[t] = __expf(v - m_s[hh]) * rz_s[hh];
        }
        __syncthreads();
        for (int el = 0; el < nn; el++) {
            int s = sl[el];
            float v0 = hl0[(size_t)s * 512 + t];
            float v1 = hl0[(size_t)s * 512 + t + 256];
            #pragma unroll
            for (int hh = 0; hh < 8; hh++) {
                float a = al[el * 8 + hh];
                acc[hh][0] = fmaf(a, v0, acc[hh][0]);
                acc[hh][1] = fmaf(a, v1, acc[hh][1]);
            }
        }
    }
    size_t dl = blockIdx.x;
    #pragma unroll
    for (int hh = 0; hh < 8; hh++) {
        u16 hh0, ll0, hh1, ll1;
        split2(acc[hh][0], hh0, ll0);
        split2(acc[hh][1], hh1, ll1);
        aggh[dl * 4096 + hh * 512 + t] = hh0;
        aggl[dl * 4096 + hh * 512 + t] = ll0;
        aggh[dl * 4096 + hh * 512 + t + 256] = hh1;
        aggl[dl * 4096 + hh * 512 + t + 256] = ll1;
    }
}

// ------------------------------- launcher ----------------------------------
extern "C" void kernel_launch(void* const* d_in, const int* in_sizes, int n_in,
                              void* d_out, int out_size, void* d_ws, size_t ws_size,
                              hipStream_t stream) {
    const float* x = (const float*)d_in[0];
    const int* ei = (const int*)d_in[1];
    const float* W0 = (const float*)d_in[2];
    const float* at_s0 = (const float*)d_in[3];
    const float* at_d0 = (const float*)d_in[4];
    const float* b0 = (const float*)d_in[5];
    const float* W1 = (const float*)d_in[6];
    const float* at_s1 = (const float*)d_in[7];
    const float* at_d1 = (const float*)d_in[8];
    const float* b1 = (const float*)d_in[9];
    float* out = (float*)d_out;

    const int N = NNODES;
    const int E = in_sizes[1] / 2;
    const int* esrc = ei;
    const int* edst = ei + E;

    char* p = (char*)d_ws;
    auto carve = [&](size_t bytes) -> void* {
        void* r = (void*)p;
        p += ((bytes + 255) & ~(size_t)255);
        return r;
    };
    float* h0 = (float*)carve((size_t)N * 512 * 4);
    float* hl0 = (float*)carve((size_t)N * 512 * 4);
    float* as0 = (float*)carve((size_t)N * 8 * 4);
    float* ad0 = (float*)carve((size_t)N * 8 * 4);
    float* as1 = (float*)carve((size_t)N * 8 * 4);
    float* ad1 = (float*)carve((size_t)N * 8 * 4);
    int* deg = (int*)carve((size_t)N * 4);
    int* indptr = (int*)carve((size_t)(N + 1) * 4);
    int* cursor = (int*)carve((size_t)N * 4);
    int* csr = (int*)carve((size_t)E * 4);
    float* ws1 = (float*)carve(512 * 8 * 4);
    float* wd1 = (float*)carve(512 * 8 * 4);
    u16* xh = (u16*)carve((size_t)N * 512 * 2);
    u16* xl = (u16*)carve((size_t)N * 512 * 2);
    u16* W0h = (u16*)carve((size_t)512 * 512 * 2);
    u16* W0l = (u16*)carve((size_t)512 * 512 * 2);
    u16* B1h = (u16*)carve((size_t)512 * 4096 * 2);
    u16* B1l = (u16*)carve((size_t)512 * 4096 * 2);
    size_t used = (size_t)(p - (char*)d_ws);

    int CH = 1024;
    const int cands[5] = {16384, 8192, 4096, 2048, 1024};
    for (int ci = 0; ci < 5; ci++) {
        if (ws_size >= used + (size_t)cands[ci] * 4096 * 4 + 512) {
            CH = cands[ci];
            break;
        }
    }
    u16* aggh = (u16*)carve((size_t)CH * 4096 * 2);
    u16* aggl = (u16*)carve((size_t)CH * 4096 * 2);

    // CSR build
    zero_k<<<(N + 255) / 256, 256, 0, stream>>>(deg, N);
    count_k<<<(E + 255) / 256, 256, 0, stream>>>(edst, E, deg);
    scan_k<<<1, 1024, 0, stream>>>(deg, indptr, cursor, N);
    scatter_k<<<(E + 255) / 256, 256, 0, stream>>>(esrc, edst, E, cursor, csr);

    // operand prep (split bf16)
    prepx_k<<<(N * 512 / 4 + 255) / 256, 256, 0, stream>>>(x, xh, xl);
    prepW0_k<<<512, 256, 0, stream>>>(W0, W0h, W0l);
    prepW1_k<<<512, 256, 0, stream>>>(W1, B1h, B1l);

    // Layer 0
    mgemm_k<0><<<dim3(4, N / 128), 256, 0, stream>>>(xh, xl, W0h, W0l, h0, 512, nullptr);
    alpha0_k<<<N, 64, 0, stream>>>(h0, at_s0, at_d0, as0, ad0);
    node0_k<<<N, 256, 0, stream>>>(h0, as0, ad0, indptr, csr, b0, hl0);

    // Layer 1 prep
    prep1_k<<<512, 256, 0, stream>>>(W1, at_s1, at_d1, ws1, wd1);
    alpha1_k<<<N, 256, 0, stream>>>(hl0, ws1, wd1, as1, ad1);

    // Layer 1: aggregate per chunk, then fused MFMA GEMM (+b1, ELU) into d_out
    for (int base = 0; base < N; base += CH) {
        node1_k<<<CH, 256, 0, stream>>>(hl0, as1, ad1, indptr, csr, aggh, aggl, base);
        mgemm_k<1><<<dim3(4, CH / 128), 256, 0, stream>>>(
            aggh, aggl, B1h, B1l, out + (size_t)base * 512, 4096, b1);
    }
}

// Round 3
// 845.084 us; speedup vs baseline: 2.1883x; 1.1597x over previous
//
#include <hip/hip_runtime.h>
#include <hip/hip_bf16.h>

// ---------------------------------------------------------------------------
// GAT 2-layer, N=16384 nodes, D=512, H=8, E=524288 edges (+self loops)
// GEMMs: split-bf16 3-term MFMA. Node kernels: CSR softmax + float4 gather.
// alpha1 fused into node0 epilogue (hl0 is in registers there).
// ---------------------------------------------------------------------------

#define NNODES 16384

typedef unsigned short u16;
typedef unsigned int u32;
typedef __attribute__((ext_vector_type(8))) __bf16 bf16x8;
typedef __attribute__((ext_vector_type(4))) float f32x4;

__device__ __forceinline__ u16 f2bf(float v) {
    u32 u = __builtin_bit_cast(u32, v);
    u32 r = (u + 0x7fffu + ((u >> 16) & 1u)) >> 16;
    return (u16)r;
}
__device__ __forceinline__ float bf2f(u16 s) {
    u32 u = ((u32)s) << 16;
    return __builtin_bit_cast(float, u);
}
__device__ __forceinline__ void split2(float v, u16& h, u16& l) {
    h = f2bf(v);
    l = f2bf(v - bf2f(h));
}

// ------------------------------ CSR build ---------------------------------
__global__ void zero_k(int* p, int n) {
    int i = blockIdx.x * 256 + threadIdx.x;
    if (i < n) p[i] = 0;
}

__global__ void count_k(const int* __restrict__ dst, int E, int* __restrict__ deg) {
    int i = blockIdx.x * 256 + threadIdx.x;
    if (i < E) atomicAdd(&deg[dst[i]], 1);
}

__global__ __launch_bounds__(1024) void scan_k(const int* __restrict__ deg,
                                               int* __restrict__ indptr,
                                               int* __restrict__ cursor, int n) {
    __shared__ int sums[1024];
    int t = threadIdx.x;
    int base = t * 16;
    int local[16];
    int s = 0;
    #pragma unroll
    for (int i = 0; i < 16; i++) { local[i] = s; s += deg[base + i]; }
    sums[t] = s;
    __syncthreads();
    for (int off = 1; off < 1024; off <<= 1) {
        int v = (t >= off) ? sums[t - off] : 0;
        __syncthreads();
        sums[t] += v;
        __syncthreads();
    }
    int base_sum = (t == 0) ? 0 : sums[t - 1];
    #pragma unroll
    for (int i = 0; i < 16; i++) {
        int v = base_sum + local[i];
        indptr[base + i] = v;
        cursor[base + i] = v;
    }
    if (t == 1023) indptr[n] = base_sum + s;
}

__global__ void scatter_k(const int* __restrict__ src, const int* __restrict__ dst,
                          int E, int* __restrict__ cursor, int* __restrict__ csr) {
    int i = blockIdx.x * 256 + threadIdx.x;
    if (i < E) {
        int pos = atomicAdd(&cursor[dst[i]], 1);
        csr[pos] = src[i];
    }
}

// ------------------------- split-bf16 prep kernels -------------------------
__global__ void prepx_k(const float* __restrict__ x, u16* __restrict__ xh,
                        u16* __restrict__ xl) {
    int idx = blockIdx.x * 256 + threadIdx.x;
    int e = idx << 2;
    int n = e >> 9, k = e & 511;
    int g = n >> 10, s = n & 1023;
    float4 v = *(const float4*)(x + ((size_t)(s * 16 + g) << 9) + k);
    u16 h[4], l[4];
    split2(v.x, h[0], l[0]);
    split2(v.y, h[1], l[1]);
    split2(v.z, h[2], l[2]);
    split2(v.w, h[3], l[3]);
    size_t o = ((size_t)n << 9) + k;
    *(ushort4*)(xh + o) = make_ushort4(h[0], h[1], h[2], h[3]);
    *(ushort4*)(xl + o) = make_ushort4(l[0], l[1], l[2], l[3]);
}

__global__ __launch_bounds__(256) void prepW0_k(const float* __restrict__ W0,
                                                u16* __restrict__ Wh,
                                                u16* __restrict__ Wl) {
    int n = blockIdx.x;
    for (int k = threadIdx.x; k < 512; k += 256) {
        float v = W0[(size_t)k * 512 + n];
        u16 h, l;
        split2(v, h, l);
        Wh[(size_t)n * 512 + k] = h;
        Wl[(size_t)n * 512 + k] = l;
    }
}

__global__ __launch_bounds__(256) void prepW1_k(const float* __restrict__ W1,
                                                u16* __restrict__ Bh,
                                                u16* __restrict__ Bl) {
    int c = blockIdx.x;
    for (int j = threadIdx.x; j < 4096; j += 256) {
        int hh = j >> 9, k = j & 511;
        float v = W1[(size_t)k * 4096 + hh * 512 + c] * 0.125f;
        u16 h, l;
        split2(v, h, l);
        Bh[(size_t)c * 4096 + j] = h;
        Bl[(size_t)c * 4096 + j] = l;
    }
}

// ---------------------------------------------------------------------------
// Split-bf16 MFMA GEMM: C[M,512] = A[M,K] @ Bt[512,K]^T  (3 MFMA per frag pair)
// ---------------------------------------------------------------------------
template <int MODE>
__global__ __launch_bounds__(256) void mgemm_k(
    const u16* __restrict__ Ah, const u16* __restrict__ Al,
    const u16* __restrict__ Bh, const u16* __restrict__ Bl,
    float* __restrict__ C, int K, const float* __restrict__ bias) {
    __shared__ u16 sAh[128 * 40], sAl[128 * 40], sBh[128 * 40], sBl[128 * 40];
    int t = threadIdx.x;
    int lane = t & 63, w = t >> 6;
    int wr = w >> 1, wc = w & 1;
    int row0 = blockIdx.y * 128, col0 = blockIdx.x * 128;

    f32x4 acc[4][4];
    #pragma unroll
    for (int i = 0; i < 4; i++)
        #pragma unroll
        for (int j = 0; j < 4; j++) acc[i][j] = (f32x4){0.f, 0.f, 0.f, 0.f};

    int srow = t >> 2;
    int sslot = t & 3;

    for (int k0 = 0; k0 < K; k0 += 32) {
        #pragma unroll
        for (int hf = 0; hf < 2; hf++) {
            int r = srow + hf * 64;
            size_t ga = (size_t)(row0 + r) * K + k0 + sslot * 8;
            size_t gb = (size_t)(col0 + r) * K + k0 + sslot * 8;
            int lo = r * 40 + sslot * 8;
            int4 vah = *(const int4*)(Ah + ga);
            int4 val = *(const int4*)(Al + ga);
            int4 vbh = *(const int4*)(Bh + gb);
            int4 vbl = *(const int4*)(Bl + gb);
            *(int4*)(sAh + lo) = vah;
            *(int4*)(sAl + lo) = val;
            *(int4*)(sBh + lo) = vbh;
            *(int4*)(sBl + lo) = vbl;
        }
        __syncthreads();

        bf16x8 afh[4], afl[4], bfh[4], bfl[4];
        int arow = wr * 64 + (lane & 15);
        int brow = wc * 64 + (lane & 15);
        int kb = lane >> 4;
        #pragma unroll
        for (int f = 0; f < 4; f++) {
            int ra = (arow + f * 16) * 40 + kb * 8;
            int rb = (brow + f * 16) * 40 + kb * 8;
            afh[f] = *(const bf16x8*)(sAh + ra);
            afl[f] = *(const bf16x8*)(sAl + ra);
            bfh[f] = *(const bf16x8*)(sBh + rb);
            bfl[f] = *(const bf16x8*)(sBl + rb);
        }
        #pragma unroll
        for (int i = 0; i < 4; i++)
            #pragma unroll
            for (int j = 0; j < 4; j++) {
                acc[i][j] = __builtin_amdgcn_mfma_f32_16x16x32_bf16(afl[i], bfh[j], acc[i][j], 0, 0, 0);
                acc[i][j] = __builtin_amdgcn_mfma_f32_16x16x32_bf16(afh[i], bfl[j], acc[i][j], 0, 0, 0);
                acc[i][j] = __builtin_amdgcn_mfma_f32_16x16x32_bf16(afh[i], bfh[j], acc[i][j], 0, 0, 0);
            }
        __syncthreads();
    }

    int cr = (lane >> 4) * 4;
    int cc = lane & 15;
    #pragma unroll
    for (int i = 0; i < 4; i++) {
        #pragma unroll
        for (int j = 0; j < 4; j++) {
            int col = col0 + wc * 64 + j * 16 + cc;
            float bv = (MODE == 1) ? bias[col] : 0.f;
            f32x4 v = acc[i][j];
            #pragma unroll
            for (int q = 0; q < 4; q++) {
                float o = v[q] + bv;
                if (MODE == 1) o = o > 0.f ? o : __expf(o) - 1.f;
                size_t grow = (size_t)(row0 + wr * 64 + i * 16 + cr + q);
                C[grow * 512 + col] = o;
            }
        }
    }
}

// ------------------------------ attention ---------------------------------
// alpha0: 4 nodes per block, one wave each
__global__ __launch_bounds__(256) void alpha0_k(const float* __restrict__ h0,
                                                const float* __restrict__ att_s,
                                                const float* __restrict__ att_d,
                                                float* __restrict__ as_,
                                                float* __restrict__ ad_) {
    int n = blockIdx.x * 4 + (threadIdx.x >> 6);
    int l = threadIdx.x & 63;
    int h = l >> 3, i = l & 7;
    float ps = 0.f, pd = 0.f;
    #pragma unroll
    for (int c = 0; c < 64; c += 8) {
        float v = h0[(size_t)n * 512 + h * 64 + c + i];
        ps += v * att_s[h * 64 + c + i];
        pd += v * att_d[h * 64 + c + i];
    }
    #pragma unroll
    for (int off = 1; off < 8; off <<= 1) {
        ps += __shfl_xor(ps, off);
        pd += __shfl_xor(pd, off);
    }
    if (i == 0) {
        as_[n * 8 + h] = ps;
        ad_[n * 8 + h] = pd;
    }
}

// folded attention weights: ws1[k,h] = sum_c W1[k, h*512+c]*att[h,c]
__global__ __launch_bounds__(256) void prep1_k(const float* __restrict__ W1,
                                               const float* __restrict__ as1,
                                               const float* __restrict__ ad1,
                                               float* __restrict__ ws1,
                                               float* __restrict__ wd1) {
    int k = blockIdx.x;
    int t = threadIdx.x;
    int h = t >> 5, lane = t & 31;
    float ps = 0.f, pd = 0.f;
    for (int c = lane; c < 512; c += 32) {
        float w = W1[(size_t)k * 4096 + h * 512 + c];
        ps += w * as1[h * 512 + c];
        pd += w * ad1[h * 512 + c];
    }
    #pragma unroll
    for (int off = 1; off < 32; off <<= 1) {
        ps += __shfl_xor(ps, off);
        pd += __shfl_xor(pd, off);
    }
    if (lane == 0) {
        ws1[k * 8 + h] = ps;
        wd1[k * 8 + h] = pd;
    }
}

// -------- layer-0 node kernel: softmax + aggregate + ELU + fused alpha1 ----
__global__ __launch_bounds__(256) void node0_k(
    const float* __restrict__ h0, const float* __restrict__ asrc,
    const float* __restrict__ adst, const int* __restrict__ indptr,
    const int* __restrict__ csr, const float* __restrict__ b0,
    const float* __restrict__ ws1, const float* __restrict__ wd1,
    float* __restrict__ hl0, float* __restrict__ as1, float* __restrict__ ad1) {
    int d = blockIdx.x;
    int t = threadIdx.x;
    __shared__ float red[256];
    __shared__ float m_s[8], rz_s[8];
    __shared__ float al[32 * 8];
    __shared__ int sl[32];
    __shared__ float comb[128 * 4];
    __shared__ float pw[2][16];
    int e0 = indptr[d], ne = indptr[d + 1] - e0;
    int h = t & 7, slice = t >> 3;
    float adh = adst[d * 8 + h];

    float mx = -3.0e38f;
    for (int e = slice; e < ne + 1; e += 32) {
        int s = (e < ne) ? csr[e0 + e] : d;
        float v = asrc[s * 8 + h] + adh;
        v = v > 0.f ? v : 0.2f * v;
        mx = fmaxf(mx, v);
    }
    red[t] = mx;
    __syncthreads();
    #pragma unroll
    for (int off = 128; off >= 8; off >>= 1) {
        if (t < off) red[t] = fmaxf(red[t], red[t + off]);
        __syncthreads();
    }
    if (t < 8) m_s[t] = red[t];
    __syncthreads();

    float mh = m_s[h];
    float zs = 0.f;
    for (int e = slice; e < ne + 1; e += 32) {
        int s = (e < ne) ? csr[e0 + e] : d;
        float v = asrc[s * 8 + h] + adh;
        v = v > 0.f ? v : 0.2f * v;
        zs += __expf(v - mh);
    }
    red[t] = zs;
    __syncthreads();
    #pragma unroll
    for (int off = 128; off >= 8; off >>= 1) {
        if (t < off) red[t] += red[t + off];
        __syncthreads();
    }
    if (t < 8) rz_s[t] = 1.0f / (red[t] + 1e-16f);
    __syncthreads();

    // gather-aggregate: 2 edges in flight (t>>7), float4 channels 4*c4..
    int half = t >> 7, c4 = t & 127;
    int hc = c4 >> 4;
    float4 acc4 = make_float4(0.f, 0.f, 0.f, 0.f);
    for (int eb = 0; eb < ne + 1; eb += 32) {
        int nn = min(32, ne + 1 - eb);
        __syncthreads();
        if (t < nn * 8) {  // t = el*8 + hh
            int el = t >> 3, hh = t & 7;
            int s = (eb + el < ne) ? csr[e0 + eb + el] : d;
            if (hh == 0) sl[el] = s;
            float v = asrc[s * 8 + hh] + adst[d * 8 + hh];
            v = v > 0.f ? v : 0.2f * v;
            al[t] = __expf(v - m_s[hh]) * rz_s[hh];
        }
        __syncthreads();
        for (int el = half; el < nn; el += 2) {
            int s = sl[el];
            float a = al[el * 8 + hc];
            float4 v = *(const float4*)(h0 + ((size_t)s << 9) + 4 * c4);
            acc4.x = fmaf(a, v.x, acc4.x);
            acc4.y = fmaf(a, v.y, acc4.y);
            acc4.z = fmaf(a, v.z, acc4.z);
            acc4.w = fmaf(a, v.w, acc4.w);
        }
    }
    if (half) *(float4*)&comb[c4 * 4] = acc4;
    __syncthreads();
    if (!half) {
        float4 c2 = *(const float4*)&comb[c4 * 4];
        float4 bv = *(const float4*)(b0 + 4 * c4);
        float4 o;
        o.x = acc4.x + c2.x + bv.x;
        o.y = acc4.y + c2.y + bv.y;
        o.z = acc4.z + c2.z + bv.z;
        o.w = acc4.w + c2.w + bv.w;
        o.x = o.x > 0.f ? o.x : __expf(o.x) - 1.f;
        o.y = o.y > 0.f ? o.y : __expf(o.y) - 1.f;
        o.z = o.z > 0.f ? o.z : __expf(o.z) - 1.f;
        o.w = o.w > 0.f ? o.w : __expf(o.w) - 1.f;
        *(float4*)(hl0 + ((size_t)d << 9) + 4 * c4) = o;

        // fused alpha1: ps[h] = sum_c o[c]*ws1[c*8+h]  (coalesced table reads)
        float ps[8] = {}, pd[8] = {};
        float oq[4] = {o.x, o.y, o.z, o.w};
        #pragma unroll
        for (int q = 0; q < 4; q++) {
            const float4* w4 = (const float4*)(ws1 + (size_t)(4 * c4 + q) * 8);
            const float4* v4 = (const float4*)(wd1 + (size_t)(4 * c4 + q) * 8);
            float4 wa = w4[0], wb = w4[1];
            float4 va = v4[0], vb = v4[1];
            ps[0] = fmaf(oq[q], wa.x, ps[0]);
            ps[1] = fmaf(oq[q], wa.y, ps[1]);
            ps[2] = fmaf(oq[q], wa.z, ps[2]);
            ps[3] = fmaf(oq[q], wa.w, ps[3]);
            ps[4] = fmaf(oq[q], wb.x, ps[4]);
            ps[5] = fmaf(oq[q], wb.y, ps[5]);
            ps[6] = fmaf(oq[q], wb.z, ps[6]);
            ps[7] = fmaf(oq[q], wb.w, ps[7]);
            pd[0] = fmaf(oq[q], va.x, pd[0]);
            pd[1] = fmaf(oq[q], va.y, pd[1]);
            pd[2] = fmaf(oq[q], va.z, pd[2]);
            pd[3] = fmaf(oq[q], va.w, pd[3]);
            pd[4] = fmaf(oq[q], vb.x, pd[4]);
            pd[5] = fmaf(oq[q], vb.y, pd[5]);
            pd[6] = fmaf(oq[q], vb.z, pd[6]);
            pd[7] = fmaf(oq[q], vb.w, pd[7]);
        }
        #pragma unroll
        for (int off = 1; off < 64; off <<= 1) {
            #pragma unroll
            for (int hh = 0; hh < 8; hh++) {
                ps[hh] += __shfl_xor(ps[hh], off);
                pd[hh] += __shfl_xor(pd[hh], off);
            }
        }
        if ((t & 63) == 0) {
            int wv = t >> 6;
            #pragma unroll
            for (int hh = 0; hh < 8; hh++) {
                pw[wv][hh] = ps[hh];
                pw[wv][8 + hh] = pd[hh];
            }
        }
    }
    __syncthreads();
    if (t < 8) as1[(size_t)d * 8 + t] = pw[0][t] + pw[1][t];
    else if (t < 16) ad1[(size_t)d * 8 + t - 8] = pw[0][t] + pw[1][t];
}

// -------- layer-1 node kernel: softmax + per-head aggregate -> split bf16 ---
__global__ __launch_bounds__(256) void node1_k(const float* __restrict__ hl0,
                                               const float* __restrict__ asrc,
                                               const float* __restrict__ adst,
                                               const int* __restrict__ indptr,
                                               const int* __restrict__ csr,
                                               u16* __restrict__ aggh,
                                               u16* __restrict__ aggl, int base) {
    int d = base + blockIdx.x;
    int t = threadIdx.x;
    __shared__ float red[256];
    __shared__ float m_s[8], rz_s[8];
    __shared__ float al[32 * 8];
    __shared__ int sl[32];
    __shared__ float comb1[8][128 * 4];
    int e0 = indptr[d], ne = indptr[d + 1] - e0;
    int h = t & 7, slice = t >> 3;
    float adh = adst[d * 8 + h];

    float mx = -3.0e38f;
    for (int e = slice; e < ne + 1; e += 32) {
        int s = (e < ne) ? csr[e0 + e] : d;
        float v = asrc[s * 8 + h] + adh;
        v = v > 0.f ? v : 0.2f * v;
        mx = fmaxf(mx, v);
    }
    red[t] = mx;
    __syncthreads();
    #pragma unroll
    for (int off = 128; off >= 8; off >>= 1) {
        if (t < off) red[t] = fmaxf(red[t], red[t + off]);
        __syncthreads();
    }
    if (t < 8) m_s[t] = red[t];
    __syncthreads();

    float mh = m_s[h];
    float zs = 0.f;
    for (int e = slice; e < ne + 1; e += 32) {
        int s = (e < ne) ? csr[e0 + e] : d;
        float v = asrc[s * 8 + h] + adh;
        v = v > 0.f ? v : 0.2f * v;
        zs += __expf(v - mh);
    }
    red[t] = zs;
    __syncthreads();
    #pragma unroll
    for (int off = 128; off >= 8; off >>= 1) {
        if (t < off) red[t] += red[t + off];
        __syncthreads();
    }
    if (t < 8) rz_s[t] = 1.0f / (red[t] + 1e-16f);
    __syncthreads();

    int half = t >> 7, c4 = t & 127;
    float4 acc[8];
    #pragma unroll
    for (int hh = 0; hh < 8; hh++) acc[hh] = make_float4(0.f, 0.f, 0.f, 0.f);

    for (int eb = 0; eb < ne + 1; eb += 32) {
        int nn = min(32, ne + 1 - eb);
        __syncthreads();
        if (t < nn * 8) {
            int el = t >> 3, hh = t & 7;
            int s = (eb + el < ne) ? csr[e0 + eb + el] : d;
            if (hh == 0) sl[el] = s;
            float v = asrc[s * 8 + hh] + adst[d * 8 + hh];
            v = v > 0.f ? v : 0.2f * v;
            al[t] = __expf(v - m_s[hh]) * rz_s[hh];
        }
        __syncthreads();
        for (int el = half; el < nn; el += 2) {
            int s = sl[el];
            float4 v = *(const float4*)(hl0 + ((size_t)s << 9) + 4 * c4);
            float4 a0 = *(const float4*)&al[el * 8];
            float4 a1 = *(const float4*)&al[el * 8 + 4];
            float av[8] = {a0.x, a0.y, a0.z, a0.w, a1.x, a1.y, a1.z, a1.w};
            #pragma unroll
            for (int hh = 0; hh < 8; hh++) {
                acc[hh].x = fmaf(av[hh], v.x, acc[hh].x);
                acc[hh].y = fmaf(av[hh], v.y, acc[hh].y);
                acc[hh].z = fmaf(av[hh], v.z, acc[hh].z);
                acc[hh].w = fmaf(av[hh], v.w, acc[hh].w);
            }
        }
    }
    if (half) {
        #pragma unroll
        for (int hh = 0; hh < 8; hh++) *(float4*)&comb1[hh][c4 * 4] = acc[hh];
    }
    __syncthreads();
    if (!half) {
        size_t dl = blockIdx.x;
        #pragma unroll
        for (int hh = 0; hh < 8; hh++) {
            float4 c2 = *(const float4*)&comb1[hh][c4 * 4];
            float4 v;
            v.x = acc[hh].x + c2.x;
            v.y = acc[hh].y + c2.y;
            v.z = acc[hh].z + c2.z;
            v.w = acc[hh].w + c2.w;
            u16 hx[4], lx[4];
            split2(v.x, hx[0], lx[0]);
            split2(v.y, hx[1], lx[1]);
            split2(v.z, hx[2], lx[2]);
            split2(v.w, hx[3], lx[3]);
            size_t ob = dl * 4096 + hh * 512 + 4 * c4;
            *(ushort4*)(aggh + ob) = make_ushort4(hx[0], hx[1], hx[2], hx[3]);
            *(ushort4*)(aggl + ob) = make_ushort4(lx[0], lx[1], lx[2], lx[3]);
        }
    }
}

// ------------------------------- launcher ----------------------------------
extern "C" void kernel_launch(void* const* d_in, const int* in_sizes, int n_in,
                              void* d_out, int out_size, void* d_ws, size_t ws_size,
                              hipStream_t stream) {
    const float* x = (const float*)d_in[0];
    const int* ei = (const int*)d_in[1];
    const float* W0 = (const float*)d_in[2];
    const float* at_s0 = (const float*)d_in[3];
    const float* at_d0 = (const float*)d_in[4];
    const float* b0 = (const float*)d_in[5];
    const float* W1 = (const float*)d_in[6];
    const float* at_s1 = (const float*)d_in[7];
    const float* at_d1 = (const float*)d_in[8];
    const float* b1 = (const float*)d_in[9];
    float* out = (float*)d_out;

    const int N = NNODES;
    const int E = in_sizes[1] / 2;
    const int* esrc = ei;
    const int* edst = ei + E;

    char* p = (char*)d_ws;
    auto carve = [&](size_t bytes) -> void* {
        void* r = (void*)p;
        p += ((bytes + 255) & ~(size_t)255);
        return r;
    };
    float* h0 = (float*)carve((size_t)N * 512 * 4);
    float* hl0 = (float*)carve((size_t)N * 512 * 4);
    float* as0 = (float*)carve((size_t)N * 8 * 4);
    float* ad0 = (float*)carve((size_t)N * 8 * 4);
    float* as1 = (float*)carve((size_t)N * 8 * 4);
    float* ad1 = (float*)carve((size_t)N * 8 * 4);
    int* deg = (int*)carve((size_t)N * 4);
    int* indptr = (int*)carve((size_t)(N + 1) * 4);
    int* cursor = (int*)carve((size_t)N * 4);
    int* csr = (int*)carve((size_t)E * 4);
    float* ws1 = (float*)carve(512 * 8 * 4);
    float* wd1 = (float*)carve(512 * 8 * 4);
    u16* xh = (u16*)carve((size_t)N * 512 * 2);
    u16* xl = (u16*)carve((size_t)N * 512 * 2);
    u16* W0h = (u16*)carve((size_t)512 * 512 * 2);
    u16* W0l = (u16*)carve((size_t)512 * 512 * 2);
    u16* B1h = (u16*)carve((size_t)512 * 4096 * 2);
    u16* B1l = (u16*)carve((size_t)512 * 4096 * 2);
    size_t used = (size_t)(p - (char*)d_ws);

    int CH = 1024;
    const int cands[5] = {16384, 8192, 4096, 2048, 1024};
    for (int ci = 0; ci < 5; ci++) {
        if (ws_size >= used + (size_t)cands[ci] * 4096 * 4 + 512) {
            CH = cands[ci];
            break;
        }
    }
    u16* aggh = (u16*)carve((size_t)CH * 4096 * 2);
    u16* aggl = (u16*)carve((size_t)CH * 4096 * 2);

    // CSR build
    zero_k<<<(N + 255) / 256, 256, 0, stream>>>(deg, N);
    count_k<<<(E + 255) / 256, 256, 0, stream>>>(edst, E, deg);
    scan_k<<<1, 1024, 0, stream>>>(deg, indptr, cursor, N);
    scatter_k<<<(E + 255) / 256, 256, 0, stream>>>(esrc, edst, E, cursor, csr);

    // operand prep (split bf16) + folded layer-1 attention weights
    prepx_k<<<(N * 512 / 4 + 255) / 256, 256, 0, stream>>>(x, xh, xl);
    prepW0_k<<<512, 256, 0, stream>>>(W0, W0h, W0l);
    prepW1_k<<<512, 256, 0, stream>>>(W1, B1h, B1l);
    prep1_k<<<512, 256, 0, stream>>>(W1, at_s1, at_d1, ws1, wd1);

    // Layer 0
    mgemm_k<0><<<dim3(4, N / 128), 256, 0, stream>>>(xh, xl, W0h, W0l, h0, 512, nullptr);
    alpha0_k<<<N / 4, 256, 0, stream>>>(h0, at_s0, at_d0, as0, ad0);
    node0_k<<<N, 256, 0, stream>>>(h0, as0, ad0, indptr, csr, b0, ws1, wd1,
                                   hl0, as1, ad1);

    // Layer 1: aggregate per chunk, then fused MFMA GEMM (+b1, ELU) into d_out
    for (int base = 0; base < N; base += CH) {
        node1_k<<<CH, 256, 0, stream>>>(hl0, as1, ad1, indptr, csr, aggh, aggl, base);
        mgemm_k<1><<<dim3(4, CH / 128), 256, 0, stream>>>(
            aggh, aggl, B1h, B1l, out + (size_t)base * 512, 4096, b1);
    }
}

// Round 4
// 690.542 us; speedup vs baseline: 2.6780x; 1.2238x over previous
//
#include <hip/hip_runtime.h>
#include <hip/hip_bf16.h>

// ---------------------------------------------------------------------------
// GAT 2-layer, N=16384 nodes, D=512, H=8, E=524288 edges (+self loops)
// GEMMs: split-bf16 3-term MFMA with global_load_lds staging + XOR swizzle.
// Node kernels: CSR softmax + float4 gather. alpha1 fused into node0.
// ---------------------------------------------------------------------------

#define NNODES 16384

typedef unsigned short u16;
typedef unsigned int u32;
typedef __attribute__((ext_vector_type(8))) __bf16 bf16x8;
typedef __attribute__((ext_vector_type(4))) float f32x4;

__device__ __forceinline__ u16 f2bf(float v) {
    u32 u = __builtin_bit_cast(u32, v);
    u32 r = (u + 0x7fffu + ((u >> 16) & 1u)) >> 16;
    return (u16)r;
}
__device__ __forceinline__ float bf2f(u16 s) {
    u32 u = ((u32)s) << 16;
    return __builtin_bit_cast(float, u);
}
__device__ __forceinline__ void split2(float v, u16& h, u16& l) {
    h = f2bf(v);
    l = f2bf(v - bf2f(h));
}

// async global->LDS, 16B per lane; LDS dest is wave-uniform base + lane*16
__device__ __forceinline__ void gload_lds16(const u16* g, u16* l) {
    __builtin_amdgcn_global_load_lds(
        (__attribute__((address_space(1))) void*)(void*)(g),
        (__attribute__((address_space(3))) void*)(void*)(l), 16, 0, 0);
}

// ------------------------------ CSR build ---------------------------------
__global__ void zero_k(int* p, int n) {
    int i = blockIdx.x * 256 + threadIdx.x;
    if (i < n) p[i] = 0;
}

__global__ void count_k(const int* __restrict__ dst, int E, int* __restrict__ deg) {
    int i = blockIdx.x * 256 + threadIdx.x;
    if (i < E) atomicAdd(&deg[dst[i]], 1);
}

__global__ __launch_bounds__(1024) void scan_k(const int* __restrict__ deg,
                                               int* __restrict__ indptr,
                                               int* __restrict__ cursor, int n) {
    __shared__ int sums[1024];
    int t = threadIdx.x;
    int base = t * 16;
    int local[16];
    int s = 0;
    #pragma unroll
    for (int i = 0; i < 16; i++) { local[i] = s; s += deg[base + i]; }
    sums[t] = s;
    __syncthreads();
    for (int off = 1; off < 1024; off <<= 1) {
        int v = (t >= off) ? sums[t - off] : 0;
        __syncthreads();
        sums[t] += v;
        __syncthreads();
    }
    int base_sum = (t == 0) ? 0 : sums[t - 1];
    #pragma unroll
    for (int i = 0; i < 16; i++) {
        int v = base_sum + local[i];
        indptr[base + i] = v;
        cursor[base + i] = v;
    }
    if (t == 1023) indptr[n] = base_sum + s;
}

__global__ void scatter_k(const int* __restrict__ src, const int* __restrict__ dst,
                          int E, int* __restrict__ cursor, int* __restrict__ csr) {
    int i = blockIdx.x * 256 + threadIdx.x;
    if (i < E) {
        int pos = atomicAdd(&cursor[dst[i]], 1);
        csr[pos] = src[i];
    }
}

// ------------------------- split-bf16 prep kernels -------------------------
__global__ void prepx_k(const float* __restrict__ x, u16* __restrict__ xh,
                        u16* __restrict__ xl) {
    int idx = blockIdx.x * 256 + threadIdx.x;
    int e = idx << 2;
    int n = e >> 9, k = e & 511;
    int g = n >> 10, s = n & 1023;
    float4 v = *(const float4*)(x + ((size_t)(s * 16 + g) << 9) + k);
    u16 h[4], l[4];
    split2(v.x, h[0], l[0]);
    split2(v.y, h[1], l[1]);
    split2(v.z, h[2], l[2]);
    split2(v.w, h[3], l[3]);
    size_t o = ((size_t)n << 9) + k;
    *(ushort4*)(xh + o) = make_ushort4(h[0], h[1], h[2], h[3]);
    *(ushort4*)(xl + o) = make_ushort4(l[0], l[1], l[2], l[3]);
}

__global__ __launch_bounds__(256) void prepW0_k(const float* __restrict__ W0,
                                                u16* __restrict__ Wh,
                                                u16* __restrict__ Wl) {
    int n = blockIdx.x;
    for (int k = threadIdx.x; k < 512; k += 256) {
        float v = W0[(size_t)k * 512 + n];
        u16 h, l;
        split2(v, h, l);
        Wh[(size_t)n * 512 + k] = h;
        Wl[(size_t)n * 512 + k] = l;
    }
}

__global__ __launch_bounds__(256) void prepW1_k(const float* __restrict__ W1,
                                                u16* __restrict__ Bh,
                                                u16* __restrict__ Bl) {
    int c = blockIdx.x;
    for (int j = threadIdx.x; j < 4096; j += 256) {
        int hh = j >> 9, k = j & 511;
        float v = W1[(size_t)k * 4096 + hh * 512 + c] * 0.125f;
        u16 h, l;
        split2(v, h, l);
        Bh[(size_t)c * 4096 + j] = h;
        Bl[(size_t)c * 4096 + j] = l;
    }
}

// ---------------------------------------------------------------------------
// Split-bf16 MFMA GEMM: C[M,512] = A[M,K] @ Bt[512,K]^T  (3 MFMA per frag pair)
// BM=64, BN=128, BK=32, 4 waves (2x2; wave = 32 rows x 64 cols).
// Staging: global_load_lds 16B, linear LDS dest, XOR-swizzled k-slot applied
// to the global SOURCE address and again on the ds_read side (T21 discipline).
// ---------------------------------------------------------------------------
template <int MODE>
__global__ __launch_bounds__(256) void mgemm_k(
    const u16* __restrict__ Ah, const u16* __restrict__ Al,
    const u16* __restrict__ Bh, const u16* __restrict__ Bl,
    float* __restrict__ C, int K, const float* __restrict__ bias) {
    // planes (u16 units): sAh[64*32]=2048, sAl=2048, sBh[128*32]=4096, sBl=4096
    __shared__ u16 smem[12288];
    u16* sAh = smem;
    u16* sAl = smem + 2048;
    u16* sBh = smem + 4096;
    u16* sBl = smem + 8192;

    int t = threadIdx.x;
    int lane = t & 63, w = t >> 6;
    int wr = w >> 1, wc = w & 1;
    int row0 = blockIdx.y * 64, col0 = blockIdx.x * 128;

    f32x4 acc[2][4];
    #pragma unroll
    for (int i = 0; i < 2; i++)
        #pragma unroll
        for (int j = 0; j < 4; j++) acc[i][j] = (f32x4){0.f, 0.f, 0.f, 0.f};

    // staging role per wave: plane + #segments (1 seg = 16 rows x 64B = 1KB)
    const u16* gb;
    u16* lb;
    int nseg, g0;
    if (w == 0) { gb = Ah; lb = sAh; nseg = 4; g0 = row0; }
    else if (w == 1) { gb = Al; lb = sAl; nseg = 4; g0 = row0; }
    else if (w == 2) { gb = Bh; lb = sBh; nseg = 8; g0 = col0; }
    else { gb = Bl; lb = sBl; nseg = 8; g0 = col0; }
    int srow = lane >> 2;          // row within segment
    int sl4 = lane & 3;            // 16B slot within 64B row

    int rl = lane & 15, kb = lane >> 4;

    for (int k0 = 0; k0 < K; k0 += 32) {
        // ---- async stage (linear LDS dest, swizzled global source slot) ----
        #pragma unroll
        for (int sgi = 0; sgi < 8; sgi++) {
            if (sgi < nseg) {
                int row = sgi * 16 + srow;
                int slot = sl4 ^ ((row >> 1) & 3);
                const u16* g = gb + (size_t)(g0 + row) * K + k0 + slot * 8;
                gload_lds16(g, lb + sgi * 512);
            }
        }
        __syncthreads();   // compiler inserts vmcnt(0) drain before barrier

        // ---- fragments (swizzled ds_read_b128) ----
        bf16x8 afh[2], afl[2], bfh[4], bfl[4];
        #pragma unroll
        for (int f = 0; f < 2; f++) {
            int r = wr * 32 + rl + f * 16;
            int off = r * 32 + ((kb ^ ((r >> 1) & 3)) << 3);
            afh[f] = *(const bf16x8*)(sAh + off);
            afl[f] = *(const bf16x8*)(sAl + off);
        }
        #pragma unroll
        for (int j = 0; j < 4; j++) {
            int r = wc * 64 + rl + j * 16;
            int off = r * 32 + ((kb ^ ((r >> 1) & 3)) << 3);
            bfh[j] = *(const bf16x8*)(sBh + off);
            bfl[j] = *(const bf16x8*)(sBl + off);
        }
        #pragma unroll
        for (int i = 0; i < 2; i++)
            #pragma unroll
            for (int j = 0; j < 4; j++) {
                acc[i][j] = __builtin_amdgcn_mfma_f32_16x16x32_bf16(afl[i], bfh[j], acc[i][j], 0, 0, 0);
                acc[i][j] = __builtin_amdgcn_mfma_f32_16x16x32_bf16(afh[i], bfl[j], acc[i][j], 0, 0, 0);
                acc[i][j] = __builtin_amdgcn_mfma_f32_16x16x32_bf16(afh[i], bfh[j], acc[i][j], 0, 0, 0);
            }
        __syncthreads();
    }

    int cr = kb * 4;
    #pragma unroll
    for (int i = 0; i < 2; i++) {
        #pragma unroll
        for (int j = 0; j < 4; j++) {
            int col = col0 + wc * 64 + j * 16 + rl;
            float bv = (MODE == 1) ? bias[col] : 0.f;
            f32x4 v = acc[i][j];
            #pragma unroll
            for (int q = 0; q < 4; q++) {
                float o = v[q] + bv;
                if (MODE == 1) o = o > 0.f ? o : __expf(o) - 1.f;
                size_t grow = (size_t)(row0 + wr * 32 + i * 16 + cr + q);
                C[grow * 512 + col] = o;
            }
        }
    }
}

// ------------------------------ attention ---------------------------------
__global__ __launch_bounds__(256) void alpha0_k(const float* __restrict__ h0,
                                                const float* __restrict__ att_s,
                                                const float* __restrict__ att_d,
                                                float* __restrict__ as_,
                                                float* __restrict__ ad_) {
    int n = blockIdx.x * 4 + (threadIdx.x >> 6);
    int l = threadIdx.x & 63;
    int h = l >> 3, i = l & 7;
    float ps = 0.f, pd = 0.f;
    #pragma unroll
    for (int c = 0; c < 64; c += 8) {
        float v = h0[(size_t)n * 512 + h * 64 + c + i];
        ps += v * att_s[h * 64 + c + i];
        pd += v * att_d[h * 64 + c + i];
    }
    #pragma unroll
    for (int off = 1; off < 8; off <<= 1) {
        ps += __shfl_xor(ps, off);
        pd += __shfl_xor(pd, off);
    }
    if (i == 0) {
        as_[n * 8 + h] = ps;
        ad_[n * 8 + h] = pd;
    }
}

__global__ __launch_bounds__(256) void prep1_k(const float* __restrict__ W1,
                                               const float* __restrict__ as1,
                                               const float* __restrict__ ad1,
                                               float* __restrict__ ws1,
                                               float* __restrict__ wd1) {
    int k = blockIdx.x;
    int t = threadIdx.x;
    int h = t >> 5, lane = t & 31;
    float ps = 0.f, pd = 0.f;
    for (int c = lane; c < 512; c += 32) {
        float w = W1[(size_t)k * 4096 + h * 512 + c];
        ps += w * as1[h * 512 + c];
        pd += w * ad1[h * 512 + c];
    }
    #pragma unroll
    for (int off = 1; off < 32; off <<= 1) {
        ps += __shfl_xor(ps, off);
        pd += __shfl_xor(pd, off);
    }
    if (lane == 0) {
        ws1[k * 8 + h] = ps;
        wd1[k * 8 + h] = pd;
    }
}

// -------- layer-0 node kernel: softmax + aggregate + ELU + fused alpha1 ----
__global__ __launch_bounds__(256) void node0_k(
    const float* __restrict__ h0, const float* __restrict__ asrc,
    const float* __restrict__ adst, const int* __restrict__ indptr,
    const int* __restrict__ csr, const float* __restrict__ b0,
    const float* __restrict__ ws1, const float* __restrict__ wd1,
    float* __restrict__ hl0, float* __restrict__ as1, float* __restrict__ ad1) {
    int d = blockIdx.x;
    int t = threadIdx.x;
    __shared__ float red[256];
    __shared__ float m_s[8], rz_s[8];
    __shared__ float al[32 * 8];
    __shared__ int sl[32];
    __shared__ float comb[128 * 4];
    __shared__ float pw[2][16];
    int e0 = indptr[d], ne = indptr[d + 1] - e0;
    int h = t & 7, slice = t >> 3;
    float adh = adst[d * 8 + h];

    float mx = -3.0e38f;
    for (int e = slice; e < ne + 1; e += 32) {
        int s = (e < ne) ? csr[e0 + e] : d;
        float v = asrc[s * 8 + h] + adh;
        v = v > 0.f ? v : 0.2f * v;
        mx = fmaxf(mx, v);
    }
    red[t] = mx;
    __syncthreads();
    #pragma unroll
    for (int off = 128; off >= 8; off >>= 1) {
        if (t < off) red[t] = fmaxf(red[t], red[t + off]);
        __syncthreads();
    }
    if (t < 8) m_s[t] = red[t];
    __syncthreads();

    float mh = m_s[h];
    float zs = 0.f;
    for (int e = slice; e < ne + 1; e += 32) {
        int s = (e < ne) ? csr[e0 + e] : d;
        float v = asrc[s * 8 + h] + adh;
        v = v > 0.f ? v : 0.2f * v;
        zs += __expf(v - mh);
    }
    red[t] = zs;
    __syncthreads();
    #pragma unroll
    for (int off = 128; off >= 8; off >>= 1) {
        if (t < off) red[t] += red[t + off];
        __syncthreads();
    }
    if (t < 8) rz_s[t] = 1.0f / (red[t] + 1e-16f);
    __syncthreads();

    int half = t >> 7, c4 = t & 127;
    int hc = c4 >> 4;
    float4 acc4 = make_float4(0.f, 0.f, 0.f, 0.f);
    for (int eb = 0; eb < ne + 1; eb += 32) {
        int nn = min(32, ne + 1 - eb);
        __syncthreads();
        if (t < nn * 8) {  // t = el*8 + hh
            int el = t >> 3, hh = t & 7;
            int s = (eb + el < ne) ? csr[e0 + eb + el] : d;
            if (hh == 0) sl[el] = s;
            float v = asrc[s * 8 + hh] + adst[d * 8 + hh];
            v = v > 0.f ? v : 0.2f * v;
            al[t] = __expf(v - m_s[hh]) * rz_s[hh];
        }
        __syncthreads();
        for (int el = half; el < nn; el += 2) {
            int s = sl[el];
            float a = al[el * 8 + hc];
            float4 v = *(const float4*)(h0 + ((size_t)s << 9) + 4 * c4);
            acc4.x = fmaf(a, v.x, acc4.x);
            acc4.y = fmaf(a, v.y, acc4.y);
            acc4.z = fmaf(a, v.z, acc4.z);
            acc4.w = fmaf(a, v.w, acc4.w);
        }
    }
    if (half) *(float4*)&comb[c4 * 4] = acc4;
    __syncthreads();
    if (!half) {
        float4 c2 = *(const float4*)&comb[c4 * 4];
        float4 bv = *(const float4*)(b0 + 4 * c4);
        float4 o;
        o.x = acc4.x + c2.x + bv.x;
        o.y = acc4.y + c2.y + bv.y;
        o.z = acc4.z + c2.z + bv.z;
        o.w = acc4.w + c2.w + bv.w;
        o.x = o.x > 0.f ? o.x : __expf(o.x) - 1.f;
        o.y = o.y > 0.f ? o.y : __expf(o.y) - 1.f;
        o.z = o.z > 0.f ? o.z : __expf(o.z) - 1.f;
        o.w = o.w > 0.f ? o.w : __expf(o.w) - 1.f;
        *(float4*)(hl0 + ((size_t)d << 9) + 4 * c4) = o;

        float ps[8] = {}, pd[8] = {};
        float oq[4] = {o.x, o.y, o.z, o.w};
        #pragma unroll
        for (int q = 0; q < 4; q++) {
            const float4* w4 = (const float4*)(ws1 + (size_t)(4 * c4 + q) * 8);
            const float4* v4 = (const float4*)(wd1 + (size_t)(4 * c4 + q) * 8);
            float4 wa = w4[0], wb = w4[1];
            float4 va = v4[0], vb = v4[1];
            ps[0] = fmaf(oq[q], wa.x, ps[0]);
            ps[1] = fmaf(oq[q], wa.y, ps[1]);
            ps[2] = fmaf(oq[q], wa.z, ps[2]);
            ps[3] = fmaf(oq[q], wa.w, ps[3]);
            ps[4] = fmaf(oq[q], wb.x, ps[4]);
            ps[5] = fmaf(oq[q], wb.y, ps[5]);
            ps[6] = fmaf(oq[q], wb.z, ps[6]);
            ps[7] = fmaf(oq[q], wb.w, ps[7]);
            pd[0] = fmaf(oq[q], va.x, pd[0]);
            pd[1] = fmaf(oq[q], va.y, pd[1]);
            pd[2] = fmaf(oq[q], va.z, pd[2]);
            pd[3] = fmaf(oq[q], va.w, pd[3]);
            pd[4] = fmaf(oq[q], vb.x, pd[4]);
            pd[5] = fmaf(oq[q], vb.y, pd[5]);
            pd[6] = fmaf(oq[q], vb.z, pd[6]);
            pd[7] = fmaf(oq[q], vb.w, pd[7]);
        }
        #pragma unroll
        for (int off = 1; off < 64; off <<= 1) {
            #pragma unroll
            for (int hh = 0; hh < 8; hh++) {
                ps[hh] += __shfl_xor(ps[hh], off);
                pd[hh] += __shfl_xor(pd[hh], off);
            }
        }
        if ((t & 63) == 0) {
            int wv = t >> 6;
            #pragma unroll
            for (int hh = 0; hh < 8; hh++) {
                pw[wv][hh] = ps[hh];
                pw[wv][8 + hh] = pd[hh];
            }
        }
    }
    __syncthreads();
    if (t < 8) as1[(size_t)d * 8 + t] = pw[0][t] + pw[1][t];
    else if (t < 16) ad1[(size_t)d * 8 + t - 8] = pw[0][t] + pw[1][t];
}

// -------- layer-1 node kernel: softmax + per-head aggregate -> split bf16 ---
__global__ __launch_bounds__(256) void node1_k(const float* __restrict__ hl0,
                                               const float* __restrict__ asrc,
                                               const float* __restrict__ adst,
                                               const int* __restrict__ indptr,
                                               const int* __restrict__ csr,
                                               u16* __restrict__ aggh,
                                               u16* __restrict__ aggl, int base) {
    int d = base + blockIdx.x;
    int t = threadIdx.x;
    __shared__ float red[256];
    __shared__ float m_s[8], rz_s[8];
    __shared__ float al[32 * 8];
    __shared__ int sl[32];
    __shared__ float comb1[8][128 * 4];
    int e0 = indptr[d], ne = indptr[d + 1] - e0;
    int h = t & 7, slice = t >> 3;
    float adh = adst[d * 8 + h];

    float mx = -3.0e38f;
    for (int e = slice; e < ne + 1; e += 32) {
        int s = (e < ne) ? csr[e0 + e] : d;
        float v = asrc[s * 8 + h] + adh;
        v = v > 0.f ? v : 0.2f * v;
        mx = fmaxf(mx, v);
    }
    red[t] = mx;
    __syncthreads();
    #pragma unroll
    for (int off = 128; off >= 8; off >>= 1) {
        if (t < off) red[t] = fmaxf(red[t], red[t + off]);
        __syncthreads();
    }
    if (t < 8) m_s[t] = red[t];
    __syncthreads();

    float mh = m_s[h];
    float zs = 0.f;
    for (int e = slice; e < ne + 1; e += 32) {
        int s = (e < ne) ? csr[e0 + e] : d;
        float v = asrc[s * 8 + h] + adh;
        v = v > 0.f ? v : 0.2f * v;
        zs += __expf(v - mh);
    }
    red[t] = zs;
    __syncthreads();
    #pragma unroll
    for (int off = 128; off >= 8; off >>= 1) {
        if (t < off) red[t] += red[t + off];
        __syncthreads();
    }
    if (t < 8) rz_s[t] = 1.0f / (red[t] + 1e-16f);
    __syncthreads();

    int half = t >> 7, c4 = t & 127;
    float4 acc[8];
    #pragma unroll
    for (int hh = 0; hh < 8; hh++) acc[hh] = make_float4(0.f, 0.f, 0.f, 0.f);

    for (int eb = 0; eb < ne + 1; eb += 32) {
        int nn = min(32, ne + 1 - eb);
        __syncthreads();
        if (t < nn * 8) {
            int el = t >> 3, hh = t & 7;
            int s = (eb + el < ne) ? csr[e0 + eb + el] : d;
            if (hh == 0) sl[el] = s;
            float v = asrc[s * 8 + hh] + adst[d * 8 + hh];
            v = v > 0.f ? v : 0.2f * v;
            al[t] = __expf(v - m_s[hh]) * rz_s[hh];
        }
        __syncthreads();
        for (int el = half; el < nn; el += 2) {
            int s = sl[el];
            float4 v = *(const float4*)(hl0 + ((size_t)s << 9) + 4 * c4);
            float4 a0 = *(const float4*)&al[el * 8];
            float4 a1 = *(const float4*)&al[el * 8 + 4];
            float av[8] = {a0.x, a0.y, a0.z, a0.w, a1.x, a1.y, a1.z, a1.w};
            #pragma unroll
            for (int hh = 0; hh < 8; hh++) {
                acc[hh].x = fmaf(av[hh], v.x, acc[hh].x);
                acc[hh].y = fmaf(av[hh], v.y, acc[hh].y);
                acc[hh].z = fmaf(av[hh], v.z, acc[hh].z);
                acc[hh].w = fmaf(av[hh], v.w, acc[hh].w);
            }
        }
    }
    if (half) {
        #pragma unroll
        for (int hh = 0; hh < 8; hh++) *(float4*)&comb1[hh][c4 * 4] = acc[hh];
    }
    __syncthreads();
    if (!half) {
        size_t dl = blockIdx.x;
        #pragma unroll
        for (int hh = 0; hh < 8; hh++) {
            float4 c2 = *(const float4*)&comb1[hh][c4 * 4];
            float4 v;
            v.x = acc[hh].x + c2.x;
            v.y = acc[hh].y + c2.y;
            v.z = acc[hh].z + c2.z;
            v.w = acc[hh].w + c2.w;
            u16 hx[4], lx[4];
            split2(v.x, hx[0], lx[0]);
            split2(v.y, hx[1], lx[1]);
            split2(v.z, hx[2], lx[2]);
            split2(v.w, hx[3], lx[3]);
            size_t ob = dl * 4096 + hh * 512 + 4 * c4;
            *(ushort4*)(aggh + ob) = make_ushort4(hx[0], hx[1], hx[2], hx[3]);
            *(ushort4*)(aggl + ob) = make_ushort4(lx[0], lx[1], lx[2], lx[3]);
        }
    }
}

// ------------------------------- launcher ----------------------------------
extern "C" void kernel_launch(void* const* d_in, const int* in_sizes, int n_in,
                              void* d_out, int out_size, void* d_ws, size_t ws_size,
                              hipStream_t stream) {
    const float* x = (const float*)d_in[0];
    const int* ei = (const int*)d_in[1];
    const float* W0 = (const float*)d_in[2];
    const float* at_s0 = (const float*)d_in[3];
    const float* at_d0 = (const float*)d_in[4];
    const float* b0 = (const float*)d_in[5];
    const float* W1 = (const float*)d_in[6];
    const float* at_s1 = (const float*)d_in[7];
    const float* at_d1 = (const float*)d_in[8];
    const float* b1 = (const float*)d_in[9];
    float* out = (float*)d_out;

    const int N = NNODES;
    const int E = in_sizes[1] / 2;
    const int* esrc = ei;
    const int* edst = ei + E;

    char* p = (char*)d_ws;
    auto carve = [&](size_t bytes) -> void* {
        void* r = (void*)p;
        p += ((bytes + 255) & ~(size_t)255);
        return r;
    };
    float* h0 = (float*)carve((size_t)N * 512 * 4);
    float* hl0 = (float*)carve((size_t)N * 512 * 4);
    float* as0 = (float*)carve((size_t)N * 8 * 4);
    float* ad0 = (float*)carve((size_t)N * 8 * 4);
    float* as1 = (float*)carve((size_t)N * 8 * 4);
    float* ad1 = (float*)carve((size_t)N * 8 * 4);
    int* deg = (int*)carve((size_t)N * 4);
    int* indptr = (int*)carve((size_t)(N + 1) * 4);
    int* cursor = (int*)carve((size_t)N * 4);
    int* csr = (int*)carve((size_t)E * 4);
    float* ws1 = (float*)carve(512 * 8 * 4);
    float* wd1 = (float*)carve(512 * 8 * 4);
    u16* xh = (u16*)carve((size_t)N * 512 * 2);
    u16* xl = (u16*)carve((size_t)N * 512 * 2);
    u16* W0h = (u16*)carve((size_t)512 * 512 * 2);
    u16* W0l = (u16*)carve((size_t)512 * 512 * 2);
    u16* B1h = (u16*)carve((size_t)512 * 4096 * 2);
    u16* B1l = (u16*)carve((size_t)512 * 4096 * 2);
    size_t used = (size_t)(p - (char*)d_ws);

    int CH = 1024;
    const int cands[5] = {16384, 8192, 4096, 2048, 1024};
    for (int ci = 0; ci < 5; ci++) {
        if (ws_size >= used + (size_t)cands[ci] * 4096 * 4 + 512) {
            CH = cands[ci];
            break;
        }
    }
    u16* aggh = (u16*)carve((size_t)CH * 4096 * 2);
    u16* aggl = (u16*)carve((size_t)CH * 4096 * 2);

    // CSR build
    zero_k<<<(N + 255) / 256, 256, 0, stream>>>(deg, N);
    count_k<<<(E + 255) / 256, 256, 0, stream>>>(edst, E, deg);
    scan_k<<<1, 1024, 0, stream>>>(deg, indptr, cursor, N);
    scatter_k<<<(E + 255) / 256, 256, 0, stream>>>(esrc, edst, E, cursor, csr);

    // operand prep (split bf16) + folded layer-1 attention weights
    prepx_k<<<(N * 512 / 4 + 255) / 256, 256, 0, stream>>>(x, xh, xl);
    prepW0_k<<<512, 256, 0, stream>>>(W0, W0h, W0l);
    prepW1_k<<<512, 256, 0, stream>>>(W1, B1h, B1l);
    prep1_k<<<512, 256, 0, stream>>>(W1, at_s1, at_d1, ws1, wd1);

    // Layer 0
    mgemm_k<0><<<dim3(4, N / 64), 256, 0, stream>>>(xh, xl, W0h, W0l, h0, 512, nullptr);
    alpha0_k<<<N / 4, 256, 0, stream>>>(h0, at_s0, at_d0, as0, ad0);
    node0_k<<<N, 256, 0, stream>>>(h0, as0, ad0, indptr, csr, b0, ws1, wd1,
                                   hl0, as1, ad1);

    // Layer 1: aggregate per chunk, then fused MFMA GEMM (+b1, ELU) into d_out
    for (int base = 0; base < N; base += CH) {
        node1_k<<<CH, 256, 0, stream>>>(hl0, as1, ad1, indptr, csr, aggh, aggl, base);
        mgemm_k<1><<<dim3(4, CH / 64), 256, 0, stream>>>(
            aggh, aggl, B1h, B1l, out + (size_t)base * 512, 4096, b1);
    }
}

// Round 5
// 653.642 us; speedup vs baseline: 2.8292x; 1.0565x over previous
//
#include <hip/hip_runtime.h>
#include <hip/hip_bf16.h>

// ---------------------------------------------------------------------------
// GAT 2-layer, N=16384 nodes, D=512, H=8, E=524288 edges (+self loops)
// GEMMs: split-bf16 3-term MFMA with global_load_lds staging + XOR swizzle.
// Node kernels: CSR softmax + float4 gather, XCD-pinned per graph (L2 local).
// alpha1 fused into node0.
// ---------------------------------------------------------------------------

#define NNODES 16384

typedef unsigned short u16;
typedef unsigned int u32;
typedef __attribute__((ext_vector_type(8))) __bf16 bf16x8;
typedef __attribute__((ext_vector_type(4))) float f32x4;

__device__ __forceinline__ u16 f2bf(float v) {
    u32 u = __builtin_bit_cast(u32, v);
    u32 r = (u + 0x7fffu + ((u >> 16) & 1u)) >> 16;
    return (u16)r;
}
__device__ __forceinline__ float bf2f(u16 s) {
    u32 u = ((u32)s) << 16;
    return __builtin_bit_cast(float, u);
}
__device__ __forceinline__ void split2(float v, u16& h, u16& l) {
    h = f2bf(v);
    l = f2bf(v - bf2f(h));
}

// async global->LDS, 16B per lane; LDS dest is wave-uniform base + lane*16
__device__ __forceinline__ void gload_lds16(const u16* g, u16* l) {
    __builtin_amdgcn_global_load_lds(
        (__attribute__((address_space(1))) void*)(void*)(g),
        (__attribute__((address_space(3))) void*)(void*)(l), 16, 0, 0);
}

// ------------------------------ CSR build ---------------------------------
__global__ void zero_k(int* p, int n) {
    int i = blockIdx.x * 256 + threadIdx.x;
    if (i < n) p[i] = 0;
}

__global__ void count_k(const int* __restrict__ dst, int E, int* __restrict__ deg) {
    int i = blockIdx.x * 256 + threadIdx.x;
    if (i < E) atomicAdd(&deg[dst[i]], 1);
}

__global__ __launch_bounds__(1024) void scan_k(const int* __restrict__ deg,
                                               int* __restrict__ indptr,
                                               int* __restrict__ cursor, int n) {
    __shared__ int sums[1024];
    int t = threadIdx.x;
    int base = t * 16;
    int local[16];
    int s = 0;
    #pragma unroll
    for (int i = 0; i < 16; i++) { local[i] = s; s += deg[base + i]; }
    sums[t] = s;
    __syncthreads();
    for (int off = 1; off < 1024; off <<= 1) {
        int v = (t >= off) ? sums[t - off] : 0;
        __syncthreads();
        sums[t] += v;
        __syncthreads();
    }
    int base_sum = (t == 0) ? 0 : sums[t - 1];
    #pragma unroll
    for (int i = 0; i < 16; i++) {
        int v = base_sum + local[i];
        indptr[base + i] = v;
        cursor[base + i] = v;
    }
    if (t == 1023) indptr[n] = base_sum + s;
}

__global__ void scatter_k(const int* __restrict__ src, const int* __restrict__ dst,
                          int E, int* __restrict__ cursor, int* __restrict__ csr) {
    int i = blockIdx.x * 256 + threadIdx.x;
    if (i < E) {
        int pos = atomicAdd(&cursor[dst[i]], 1);
        csr[pos] = src[i];
    }
}

// ------------------------- split-bf16 prep kernels -------------------------
__global__ void prepx_k(const float* __restrict__ x, u16* __restrict__ xh,
                        u16* __restrict__ xl) {
    int idx = blockIdx.x * 256 + threadIdx.x;
    int e = idx << 2;
    int n = e >> 9, k = e & 511;
    int g = n >> 10, s = n & 1023;
    float4 v = *(const float4*)(x + ((size_t)(s * 16 + g) << 9) + k);
    u16 h[4], l[4];
    split2(v.x, h[0], l[0]);
    split2(v.y, h[1], l[1]);
    split2(v.z, h[2], l[2]);
    split2(v.w, h[3], l[3]);
    size_t o = ((size_t)n << 9) + k;
    *(ushort4*)(xh + o) = make_ushort4(h[0], h[1], h[2], h[3]);
    *(ushort4*)(xl + o) = make_ushort4(l[0], l[1], l[2], l[3]);
}

__global__ __launch_bounds__(256) void prepW0_k(const float* __restrict__ W0,
                                                u16* __restrict__ Wh,
                                                u16* __restrict__ Wl) {
    int n = blockIdx.x;
    for (int k = threadIdx.x; k < 512; k += 256) {
        float v = W0[(size_t)k * 512 + n];
        u16 h, l;
        split2(v, h, l);
        Wh[(size_t)n * 512 + k] = h;
        Wl[(size_t)n * 512 + k] = l;
    }
}

__global__ __launch_bounds__(256) void prepW1_k(const float* __restrict__ W1,
                                                u16* __restrict__ Bh,
                                                u16* __restrict__ Bl) {
    int c = blockIdx.x;
    for (int j = threadIdx.x; j < 4096; j += 256) {
        int hh = j >> 9, k = j & 511;
        float v = W1[(size_t)k * 4096 + hh * 512 + c] * 0.125f;
        u16 h, l;
        split2(v, h, l);
        Bh[(size_t)c * 4096 + j] = h;
        Bl[(size_t)c * 4096 + j] = l;
    }
}

// ---------------------------------------------------------------------------
// Split-bf16 MFMA GEMM: C[M,512] = A[M,K] @ Bt[512,K]^T  (3 MFMA per frag pair)
// BM=64, BN=128, BK=32, 4 waves. global_load_lds + XOR swizzle (T21).
// ---------------------------------------------------------------------------
template <int MODE>
__global__ __launch_bounds__(256) void mgemm_k(
    const u16* __restrict__ Ah, const u16* __restrict__ Al,
    const u16* __restrict__ Bh, const u16* __restrict__ Bl,
    float* __restrict__ C, int K, const float* __restrict__ bias) {
    __shared__ u16 smem[12288];
    u16* sAh = smem;
    u16* sAl = smem + 2048;
    u16* sBh = smem + 4096;
    u16* sBl = smem + 8192;

    int t = threadIdx.x;
    int lane = t & 63, w = t >> 6;
    int wr = w >> 1, wc = w & 1;
    int row0 = blockIdx.y * 64, col0 = blockIdx.x * 128;

    f32x4 acc[2][4];
    #pragma unroll
    for (int i = 0; i < 2; i++)
        #pragma unroll
        for (int j = 0; j < 4; j++) acc[i][j] = (f32x4){0.f, 0.f, 0.f, 0.f};

    const u16* gb;
    u16* lb;
    int nseg, g0;
    if (w == 0) { gb = Ah; lb = sAh; nseg = 4; g0 = row0; }
    else if (w == 1) { gb = Al; lb = sAl; nseg = 4; g0 = row0; }
    else if (w == 2) { gb = Bh; lb = sBh; nseg = 8; g0 = col0; }
    else { gb = Bl; lb = sBl; nseg = 8; g0 = col0; }
    int srow = lane >> 2;
    int sl4 = lane & 3;

    int rl = lane & 15, kb = lane >> 4;

    for (int k0 = 0; k0 < K; k0 += 32) {
        #pragma unroll
        for (int sgi = 0; sgi < 8; sgi++) {
            if (sgi < nseg) {
                int row = sgi * 16 + srow;
                int slot = sl4 ^ ((row >> 1) & 3);
                const u16* g = gb + (size_t)(g0 + row) * K + k0 + slot * 8;
                gload_lds16(g, lb + sgi * 512);
            }
        }
        __syncthreads();

        bf16x8 afh[2], afl[2], bfh[4], bfl[4];
        #pragma unroll
        for (int f = 0; f < 2; f++) {
            int r = wr * 32 + rl + f * 16;
            int off = r * 32 + ((kb ^ ((r >> 1) & 3)) << 3);
            afh[f] = *(const bf16x8*)(sAh + off);
            afl[f] = *(const bf16x8*)(sAl + off);
        }
        #pragma unroll
        for (int j = 0; j < 4; j++) {
            int r = wc * 64 + rl + j * 16;
            int off = r * 32 + ((kb ^ ((r >> 1) & 3)) << 3);
            bfh[j] = *(const bf16x8*)(sBh + off);
            bfl[j] = *(const bf16x8*)(sBl + off);
        }
        #pragma unroll
        for (int i = 0; i < 2; i++)
            #pragma unroll
            for (int j = 0; j < 4; j++) {
                acc[i][j] = __builtin_amdgcn_mfma_f32_16x16x32_bf16(afl[i], bfh[j], acc[i][j], 0, 0, 0);
                acc[i][j] = __builtin_amdgcn_mfma_f32_16x16x32_bf16(afh[i], bfl[j], acc[i][j], 0, 0, 0);
                acc[i][j] = __builtin_amdgcn_mfma_f32_16x16x32_bf16(afh[i], bfh[j], acc[i][j], 0, 0, 0);
            }
        __syncthreads();
    }

    int cr = kb * 4;
    #pragma unroll
    for (int i = 0; i < 2; i++) {
        #pragma unroll
        for (int j = 0; j < 4; j++) {
            int col = col0 + wc * 64 + j * 16 + rl;
            float bv = (MODE == 1) ? bias[col] : 0.f;
            f32x4 v = acc[i][j];
            #pragma unroll
            for (int q = 0; q < 4; q++) {
                float o = v[q] + bv;
                if (MODE == 1) o = o > 0.f ? o : __expf(o) - 1.f;
                size_t grow = (size_t)(row0 + wr * 32 + i * 16 + cr + q);
                C[grow * 512 + col] = o;
            }
        }
    }
}

// ------------------------------ attention ---------------------------------
__global__ __launch_bounds__(256) void alpha0_k(const float* __restrict__ h0,
                                                const float* __restrict__ att_s,
                                                const float* __restrict__ att_d,
                                                float* __restrict__ as_,
                                                float* __restrict__ ad_) {
    int n = blockIdx.x * 4 + (threadIdx.x >> 6);
    int l = threadIdx.x & 63;
    int h = l >> 3, i = l & 7;
    float ps = 0.f, pd = 0.f;
    #pragma unroll
    for (int c = 0; c < 64; c += 8) {
        float v = h0[(size_t)n * 512 + h * 64 + c + i];
        ps += v * att_s[h * 64 + c + i];
        pd += v * att_d[h * 64 + c + i];
    }
    #pragma unroll
    for (int off = 1; off < 8; off <<= 1) {
        ps += __shfl_xor(ps, off);
        pd += __shfl_xor(pd, off);
    }
    if (i == 0) {
        as_[n * 8 + h] = ps;
        ad_[n * 8 + h] = pd;
    }
}

__global__ __launch_bounds__(256) void prep1_k(const float* __restrict__ W1,
                                               const float* __restrict__ as1,
                                               const float* __restrict__ ad1,
                                               float* __restrict__ ws1,
                                               float* __restrict__ wd1) {
    int k = blockIdx.x;
    int t = threadIdx.x;
    int h = t >> 5, lane = t & 31;
    float ps = 0.f, pd = 0.f;
    for (int c = lane; c < 512; c += 32) {
        float w = W1[(size_t)k * 4096 + h * 512 + c];
        ps += w * as1[h * 512 + c];
        pd += w * ad1[h * 512 + c];
    }
    #pragma unroll
    for (int off = 1; off < 32; off <<= 1) {
        ps += __shfl_xor(ps, off);
        pd += __shfl_xor(pd, off);
    }
    if (lane == 0) {
        ws1[k * 8 + h] = ps;
        wd1[k * 8 + h] = pd;
    }
}

// -------- layer-0 node kernel: softmax + aggregate + ELU + fused alpha1 ----
// blockIdx swizzled so each XCD (dispatch id % 8) works one graph at a time:
// its 2 MB h0 slice stays resident in the XCD-private 4 MB L2.
__global__ __launch_bounds__(256) void node0_k(
    const float* __restrict__ h0, const float* __restrict__ asrc,
    const float* __restrict__ adst, const int* __restrict__ indptr,
    const int* __restrict__ csr, const float* __restrict__ b0,
    const float* __restrict__ ws1, const float* __restrict__ wd1,
    float* __restrict__ hl0, float* __restrict__ as1, float* __restrict__ ad1) {
    int d = (blockIdx.x & 7) * (NNODES / 8) + (blockIdx.x >> 3);
    int t = threadIdx.x;
    __shared__ float red[256];
    __shared__ float m_s[8], rz_s[8];
    __shared__ float al[32 * 8];
    __shared__ int sl[32];
    __shared__ float comb[128 * 4];
    __shared__ float pw[2][16];
    int e0 = indptr[d], ne = indptr[d + 1] - e0;
    int h = t & 7, slice = t >> 3;
    float adh = adst[d * 8 + h];

    float mx = -3.0e38f;
    for (int e = slice; e < ne + 1; e += 32) {
        int s = (e < ne) ? csr[e0 + e] : d;
        float v = asrc[s * 8 + h] + adh;
        v = v > 0.f ? v : 0.2f * v;
        mx = fmaxf(mx, v);
    }
    red[t] = mx;
    __syncthreads();
    #pragma unroll
    for (int off = 128; off >= 8; off >>= 1) {
        if (t < off) red[t] = fmaxf(red[t], red[t + off]);
        __syncthreads();
    }
    if (t < 8) m_s[t] = red[t];
    __syncthreads();

    float mh = m_s[h];
    float zs = 0.f;
    for (int e = slice; e < ne + 1; e += 32) {
        int s = (e < ne) ? csr[e0 + e] : d;
        float v = asrc[s * 8 + h] + adh;
        v = v > 0.f ? v : 0.2f * v;
        zs += __expf(v - mh);
    }
    red[t] = zs;
    __syncthreads();
    #pragma unroll
    for (int off = 128; off >= 8; off >>= 1) {
        if (t < off) red[t] += red[t + off];
        __syncthreads();
    }
    if (t < 8) rz_s[t] = 1.0f / (red[t] + 1e-16f);
    __syncthreads();

    int half = t >> 7, c4 = t & 127;
    int hc = c4 >> 4;
    float4 acc4 = make_float4(0.f, 0.f, 0.f, 0.f);
    for (int eb = 0; eb < ne + 1; eb += 32) {
        int nn = min(32, ne + 1 - eb);
        __syncthreads();
        if (t < nn * 8) {  // t = el*8 + hh
            int el = t >> 3, hh = t & 7;
            int s = (eb + el < ne) ? csr[e0 + eb + el] : d;
            if (hh == 0) sl[el] = s;
            float v = asrc[s * 8 + hh] + adst[d * 8 + hh];
            v = v > 0.f ? v : 0.2f * v;
            al[t] = __expf(v - m_s[hh]) * rz_s[hh];
        }
        __syncthreads();
        for (int el = half; el < nn; el += 2) {
            int s = sl[el];
            float a = al[el * 8 + hc];
            float4 v = *(const float4*)(h0 + ((size_t)s << 9) + 4 * c4);
            acc4.x = fmaf(a, v.x, acc4.x);
            acc4.y = fmaf(a, v.y, acc4.y);
            acc4.z = fmaf(a, v.z, acc4.z);
            acc4.w = fmaf(a, v.w, acc4.w);
        }
    }
    if (half) *(float4*)&comb[c4 * 4] = acc4;
    __syncthreads();
    if (!half) {
        float4 c2 = *(const float4*)&comb[c4 * 4];
        float4 bv = *(const float4*)(b0 + 4 * c4);
        float4 o;
        o.x = acc4.x + c2.x + bv.x;
        o.y = acc4.y + c2.y + bv.y;
        o.z = acc4.z + c2.z + bv.z;
        o.w = acc4.w + c2.w + bv.w;
        o.x = o.x > 0.f ? o.x : __expf(o.x) - 1.f;
        o.y = o.y > 0.f ? o.y : __expf(o.y) - 1.f;
        o.z = o.z > 0.f ? o.z : __expf(o.z) - 1.f;
        o.w = o.w > 0.f ? o.w : __expf(o.w) - 1.f;
        *(float4*)(hl0 + ((size_t)d << 9) + 4 * c4) = o;

        float ps[8] = {}, pd[8] = {};
        float oq[4] = {o.x, o.y, o.z, o.w};
        #pragma unroll
        for (int q = 0; q < 4; q++) {
            const float4* w4 = (const float4*)(ws1 + (size_t)(4 * c4 + q) * 8);
            const float4* v4 = (const float4*)(wd1 + (size_t)(4 * c4 + q) * 8);
            float4 wa = w4[0], wb = w4[1];
            float4 va = v4[0], vb = v4[1];
            ps[0] = fmaf(oq[q], wa.x, ps[0]);
            ps[1] = fmaf(oq[q], wa.y, ps[1]);
            ps[2] = fmaf(oq[q], wa.z, ps[2]);
            ps[3] = fmaf(oq[q], wa.w, ps[3]);
            ps[4] = fmaf(oq[q], wb.x, ps[4]);
            ps[5] = fmaf(oq[q], wb.y, ps[5]);
            ps[6] = fmaf(oq[q], wb.z, ps[6]);
            ps[7] = fmaf(oq[q], wb.w, ps[7]);
            pd[0] = fmaf(oq[q], va.x, pd[0]);
            pd[1] = fmaf(oq[q], va.y, pd[1]);
            pd[2] = fmaf(oq[q], va.z, pd[2]);
            pd[3] = fmaf(oq[q], va.w, pd[3]);
            pd[4] = fmaf(oq[q], vb.x, pd[4]);
            pd[5] = fmaf(oq[q], vb.y, pd[5]);
            pd[6] = fmaf(oq[q], vb.z, pd[6]);
            pd[7] = fmaf(oq[q], vb.w, pd[7]);
        }
        #pragma unroll
        for (int off = 1; off < 64; off <<= 1) {
            #pragma unroll
            for (int hh = 0; hh < 8; hh++) {
                ps[hh] += __shfl_xor(ps[hh], off);
                pd[hh] += __shfl_xor(pd[hh], off);
            }
        }
        if ((t & 63) == 0) {
            int wv = t >> 6;
            #pragma unroll
            for (int hh = 0; hh < 8; hh++) {
                pw[wv][hh] = ps[hh];
                pw[wv][8 + hh] = pd[hh];
            }
        }
    }
    __syncthreads();
    if (t < 8) as1[(size_t)d * 8 + t] = pw[0][t] + pw[1][t];
    else if (t < 16) ad1[(size_t)d * 8 + t - 8] = pw[0][t] + pw[1][t];
}

// -------- layer-1 node kernel: softmax + per-head aggregate -> split bf16 ---
// Same XCD/graph swizzle within the chunk (CH is a multiple of 8192 here).
__global__ __launch_bounds__(256) void node1_k(const float* __restrict__ hl0,
                                               const float* __restrict__ asrc,
                                               const float* __restrict__ adst,
                                               const int* __restrict__ indptr,
                                               const int* __restrict__ csr,
                                               u16* __restrict__ aggh,
                                               u16* __restrict__ aggl,
                                               int base, int ch) {
    int dl = (blockIdx.x & 7) * (ch >> 3) + (blockIdx.x >> 3);
    int d = base + dl;
    int t = threadIdx.x;
    __shared__ float red[256];
    __shared__ float m_s[8], rz_s[8];
    __shared__ float al[32 * 8];
    __shared__ int sl[32];
    __shared__ float comb1[8][128 * 4];
    int e0 = indptr[d], ne = indptr[d + 1] - e0;
    int h = t & 7, slice = t >> 3;
    float adh = adst[d * 8 + h];

    float mx = -3.0e38f;
    for (int e = slice; e < ne + 1; e += 32) {
        int s = (e < ne) ? csr[e0 + e] : d;
        float v = asrc[s * 8 + h] + adh;
        v = v > 0.f ? v : 0.2f * v;
        mx = fmaxf(mx, v);
    }
    red[t] = mx;
    __syncthreads();
    #pragma unroll
    for (int off = 128; off >= 8; off >>= 1) {
        if (t < off) red[t] = fmaxf(red[t], red[t + off]);
        __syncthreads();
    }
    if (t < 8) m_s[t] = red[t];
    __syncthreads();

    float mh = m_s[h];
    float zs = 0.f;
    for (int e = slice; e < ne + 1; e += 32) {
        int s = (e < ne) ? csr[e0 + e] : d;
        float v = asrc[s * 8 + h] + adh;
        v = v > 0.f ? v : 0.2f * v;
        zs += __expf(v - mh);
    }
    red[t] = zs;
    __syncthreads();
    #pragma unroll
    for (int off = 128; off >= 8; off >>= 1) {
        if (t < off) red[t] += red[t + off];
        __syncthreads();
    }
    if (t < 8) rz_s[t] = 1.0f / (red[t] + 1e-16f);
    __syncthreads();

    int half = t >> 7, c4 = t & 127;
    float4 acc[8];
    #pragma unroll
    for (int hh = 0; hh < 8; hh++) acc[hh] = make_float4(0.f, 0.f, 0.f, 0.f);

    for (int eb = 0; eb < ne + 1; eb += 32) {
        int nn = min(32, ne + 1 - eb);
        __syncthreads();
        if (t < nn * 8) {
            int el = t >> 3, hh = t & 7;
            int s = (eb + el < ne) ? csr[e0 + eb + el] : d;
            if (hh == 0) sl[el] = s;
            float v = asrc[s * 8 + hh] + adst[d * 8 + hh];
            v = v > 0.f ? v : 0.2f * v;
            al[t] = __expf(v - m_s[hh]) * rz_s[hh];
        }
        __syncthreads();
        for (int el = half; el < nn; el += 2) {
            int s = sl[el];
            float4 v = *(const float4*)(hl0 + ((size_t)s << 9) + 4 * c4);
            float4 a0 = *(const float4*)&al[el * 8];
            float4 a1 = *(const float4*)&al[el * 8 + 4];
            float av[8] = {a0.x, a0.y, a0.z, a0.w, a1.x, a1.y, a1.z, a1.w};
            #pragma unroll
            for (int hh = 0; hh < 8; hh++) {
                acc[hh].x = fmaf(av[hh], v.x, acc[hh].x);
                acc[hh].y = fmaf(av[hh], v.y, acc[hh].y);
                acc[hh].z = fmaf(av[hh], v.z, acc[hh].z);
                acc[hh].w = fmaf(av[hh], v.w, acc[hh].w);
            }
        }
    }
    if (half) {
        #pragma unroll
        for (int hh = 0; hh < 8; hh++) *(float4*)&comb1[hh][c4 * 4] = acc[hh];
    }
    __syncthreads();
    if (!half) {
        #pragma unroll
        for (int hh = 0; hh < 8; hh++) {
            float4 c2 = *(const float4*)&comb1[hh][c4 * 4];
            float4 v;
            v.x = acc[hh].x + c2.x;
            v.y = acc[hh].y + c2.y;
            v.z = acc[hh].z + c2.z;
            v.w = acc[hh].w + c2.w;
            u16 hx[4], lx[4];
            split2(v.x, hx[0], lx[0]);
            split2(v.y, hx[1], lx[1]);
            split2(v.z, hx[2], lx[2]);
            split2(v.w, hx[3], lx[3]);
            size_t ob = (size_t)dl * 4096 + hh * 512 + 4 * c4;
            *(ushort4*)(aggh + ob) = make_ushort4(hx[0], hx[1], hx[2], hx[3]);
            *(ushort4*)(aggl + ob) = make_ushort4(lx[0], lx[1], lx[2], lx[3]);
        }
    }
}

// ------------------------------- launcher ----------------------------------
extern "C" void kernel_launch(void* const* d_in, const int* in_sizes, int n_in,
                              void* d_out, int out_size, void* d_ws, size_t ws_size,
                              hipStream_t stream) {
    const float* x = (const float*)d_in[0];
    const int* ei = (const int*)d_in[1];
    const float* W0 = (const float*)d_in[2];
    const float* at_s0 = (const float*)d_in[3];
    const float* at_d0 = (const float*)d_in[4];
    const float* b0 = (const float*)d_in[5];
    const float* W1 = (const float*)d_in[6];
    const float* at_s1 = (const float*)d_in[7];
    const float* at_d1 = (const float*)d_in[8];
    const float* b1 = (const float*)d_in[9];
    float* out = (float*)d_out;

    const int N = NNODES;
    const int E = in_sizes[1] / 2;
    const int* esrc = ei;
    const int* edst = ei + E;

    char* p = (char*)d_ws;
    auto carve = [&](size_t bytes) -> void* {
        void* r = (void*)p;
        p += ((bytes + 255) & ~(size_t)255);
        return r;
    };
    float* h0 = (float*)carve((size_t)N * 512 * 4);
    float* hl0 = (float*)carve((size_t)N * 512 * 4);
    float* as0 = (float*)carve((size_t)N * 8 * 4);
    float* ad0 = (float*)carve((size_t)N * 8 * 4);
    float* as1 = (float*)carve((size_t)N * 8 * 4);
    float* ad1 = (float*)carve((size_t)N * 8 * 4);
    int* deg = (int*)carve((size_t)N * 4);
    int* indptr = (int*)carve((size_t)(N + 1) * 4);
    int* cursor = (int*)carve((size_t)N * 4);
    int* csr = (int*)carve((size_t)E * 4);
    float* ws1 = (float*)carve(512 * 8 * 4);
    float* wd1 = (float*)carve(512 * 8 * 4);
    u16* xh = (u16*)carve((size_t)N * 512 * 2);
    u16* xl = (u16*)carve((size_t)N * 512 * 2);
    u16* W0h = (u16*)carve((size_t)512 * 512 * 2);
    u16* W0l = (u16*)carve((size_t)512 * 512 * 2);
    u16* B1h = (u16*)carve((size_t)512 * 4096 * 2);
    u16* B1l = (u16*)carve((size_t)512 * 4096 * 2);
    size_t used = (size_t)(p - (char*)d_ws);

    int CH = 1024;
    const int cands[5] = {16384, 8192, 4096, 2048, 1024};
    for (int ci = 0; ci < 5; ci++) {
        if (ws_size >= used + (size_t)cands[ci] * 4096 * 4 + 512) {
            CH = cands[ci];
            break;
        }
    }
    u16* aggh = (u16*)carve((size_t)CH * 4096 * 2);
    u16* aggl = (u16*)carve((size_t)CH * 4096 * 2);

    // CSR build
    zero_k<<<(N + 255) / 256, 256, 0, stream>>>(deg, N);
    count_k<<<(E + 255) / 256, 256, 0, stream>>>(edst, E, deg);
    scan_k<<<1, 1024, 0, stream>>>(deg, indptr, cursor, N);
    scatter_k<<<(E + 255) / 256, 256, 0, stream>>>(esrc, edst, E, cursor, csr);

    // operand prep (split bf16) + folded layer-1 attention weights
    prepx_k<<<(N * 512 / 4 + 255) / 256, 256, 0, stream>>>(x, xh, xl);
    prepW0_k<<<512, 256, 0, stream>>>(W0, W0h, W0l);
    prepW1_k<<<512, 256, 0, stream>>>(W1, B1h, B1l);
    prep1_k<<<512, 256, 0, stream>>>(W1, at_s1, at_d1, ws1, wd1);

    // Layer 0
    mgemm_k<0><<<dim3(4, N / 64), 256, 0, stream>>>(xh, xl, W0h, W0l, h0, 512, nullptr);
    alpha0_k<<<N / 4, 256, 0, stream>>>(h0, at_s0, at_d0, as0, ad0);
    node0_k<<<N, 256, 0, stream>>>(h0, as0, ad0, indptr, csr, b0, ws1, wd1,
                                   hl0, as1, ad1);

    // Layer 1: aggregate per chunk, then fused MFMA GEMM (+b1, ELU) into d_out
    for (int base = 0; base < N; base += CH) {
        node1_k<<<CH, 256, 0, stream>>>(hl0, as1, ad1, indptr, csr, aggh, aggl,
                                        base, CH);
        mgemm_k<1><<<dim3(4, CH / 64), 256, 0, stream>>>(
            aggh, aggl, B1h, B1l, out + (size_t)base * 512, 4096, b1);
    }
}